// Round 1
// baseline (6994.991 us; speedup 1.0000x reference)
//
#include <hip/hip_runtime.h>
#include <cstddef>
#include <cstdint>

typedef __attribute__((ext_vector_type(4))) float f32x4;
typedef __attribute__((ext_vector_type(8))) short short8;

#define HID 128

__device__ __forceinline__ short f2bf(float f) {
  unsigned u = __builtin_bit_cast(unsigned, f);
  u += 0x7FFFu + ((u >> 16) & 1u);
  return (short)(u >> 16);
}
__device__ __forceinline__ float bf2f(short s) {
  unsigned u = ((unsigned)(unsigned short)s) << 16;
  return __builtin_bit_cast(float, u);
}
__device__ __forceinline__ float sigm(float x) {
  return __builtin_amdgcn_rcpf(1.0f + __builtin_amdgcn_exp2f(-1.4426950408889634f * x));
}
__device__ __forceinline__ float tanh_(float x) {
  // tanh(x) = 1 - 2/(exp(2x)+1); saturates correctly at +/-inf of exp2
  return 1.0f - 2.0f * __builtin_amdgcn_rcpf(1.0f + __builtin_amdgcn_exp2f(2.8853900817779268f * x));
}

// ---------------- conversion kernels ----------------
__global__ void conv_x_kernel(const float* __restrict__ x, short* __restrict__ xb, int n) {
  int i = blockIdx.x * blockDim.x + threadIdx.x;
  int stride = gridDim.x * blockDim.x;
  for (; i < n; i += stride) xb[i] = f2bf(x[i]);
}

__global__ void conv_layer_kernel(const float* __restrict__ Wih, const float* __restrict__ Whh,
                                  const float* __restrict__ bih, const float* __restrict__ bhh,
                                  const float* __restrict__ Wl, const float* __restrict__ Wr, int foK,
                                  short* __restrict__ wihB, short* __restrict__ whhB,
                                  short* __restrict__ wlB, short* __restrict__ wrB,
                                  float* __restrict__ bsum) {
  int i = blockIdx.x * blockDim.x + threadIdx.x;
  if (i < 512 * HID) { wihB[i] = f2bf(Wih[i]); whhB[i] = f2bf(Whh[i]); }
  if (i < foK) { wlB[i] = f2bf(Wl[i]); wrB[i] = f2bf(Wr[i]); }
  if (i < 512) bsum[i] = bih[i] + bhh[i];
}

// ---------------- generic fused MFMA GEMM ----------------
// C[M, NC] = A1@W1^T (+ A2@W2^T) + bias, optional relu. A row-major [M,128],
// W row-major [NC,128]. 128 threads = 2 waves; wave handles 16 rows x NC cols.
template <int NTILES, bool HASB2, bool RELU, bool OUTF32>
__global__ __launch_bounds__(128, 2) void gemm_kernel(
    const short* __restrict__ A1, const short* __restrict__ W1,
    const short* __restrict__ A2, const short* __restrict__ W2,
    const float* __restrict__ bias,
    short* __restrict__ outB, float* __restrict__ outF, int M) {
  const int NC = NTILES * 16;
  const int tid = threadIdx.x;
  const int wave = tid >> 6, lane = tid & 63;
  const int quad = lane >> 4, nn = lane & 15;
  const int row0 = blockIdx.x * 32 + wave * 16;
  int arow = row0 + nn;
  if (arow > M - 1) arow = M - 1;  // clamp so OOB rows load valid memory

  const f32x4 zero4 = {0.f, 0.f, 0.f, 0.f};
  f32x4 acc[NTILES];
#pragma unroll
  for (int i = 0; i < NTILES; ++i) acc[i] = zero4;

#pragma unroll
  for (int kt = 0; kt < 4; ++kt) {
    short8 af = *(const short8*)(A1 + (size_t)arow * HID + kt * 32 + quad * 8);
#pragma unroll
    for (int nt = 0; nt < NTILES; ++nt) {
      short8 bf = *(const short8*)(W1 + (size_t)(nt * 16 + nn) * HID + kt * 32 + quad * 8);
      acc[nt] = __builtin_amdgcn_mfma_f32_16x16x32_bf16(af, bf, acc[nt], 0, 0, 0);
    }
  }
  if (HASB2) {
#pragma unroll
    for (int kt = 0; kt < 4; ++kt) {
      short8 af = *(const short8*)(A2 + (size_t)arow * HID + kt * 32 + quad * 8);
#pragma unroll
      for (int nt = 0; nt < NTILES; ++nt) {
        short8 bf = *(const short8*)(W2 + (size_t)(nt * 16 + nn) * HID + kt * 32 + quad * 8);
        acc[nt] = __builtin_amdgcn_mfma_f32_16x16x32_bf16(af, bf, acc[nt], 0, 0, 0);
      }
    }
  }
  // D layout: row m = quad*4 + r, col = nt*16 + nn  (verified m89/m91)
#pragma unroll
  for (int nt = 0; nt < NTILES; ++nt) {
    int col = nt * 16 + nn;
    float b = bias[col];
#pragma unroll
    for (int r = 0; r < 4; ++r) {
      int m = row0 + quad * 4 + r;
      if (m < M) {
        float v = acc[nt][r] + b;
        if (RELU) v = fmaxf(v, 0.0f);
        if (OUTF32) outF[(size_t)m * NC + col] = v;
        else outB[(size_t)m * NC + col] = f2bf(v);
      }
    }
  }
}

// ---------------- persistent-tile LSTM recurrence ----------------
// One block = 32 nodes, 2 waves. h kept in LDS (bf16), c in registers (f32),
// for all 16 timesteps. Per step: stage gathered P rows (1KB each) into LDS,
// G = h @ Whh^T via MFMA (Whh streamed from L1/L2 - shared by all blocks),
// LSTM cell in D-layout registers, write new h back to LDS.
#define NPB 32
#define PSTR 520  // 512 + 8 pad (breaks ldsP epilogue-read bank conflicts)
#define HSTR 136  // 128 + 8 pad

__global__ __launch_bounds__(128, 2) void lstm_steps_kernel(
    const short* __restrict__ P, const short* __restrict__ Whh,
    const int* __restrict__ src, short* __restrict__ aggr, int M) {
  __shared__ short ldsP[NPB * PSTR];  // 33280 B
  __shared__ short ldsH[NPB * HSTR];  // 8704 B
  const int tid = threadIdx.x;
  const int wave = tid >> 6, lane = tid & 63;
  const int quad = lane >> 4, nn = lane & 15;
  const int nodeBase = blockIdx.x * NPB;

  for (int i = tid; i < NPB * HSTR; i += 128) ldsH[i] = 0;  // h0 = 0

  float c_st[8][4];
#pragma unroll
  for (int nt = 0; nt < 8; ++nt)
#pragma unroll
    for (int r = 0; r < 4; ++r) c_st[nt][r] = 0.0f;

  __syncthreads();

  const f32x4 zero4 = {0.f, 0.f, 0.f, 0.f};
  f32x4 acc[32];

#pragma unroll 1
  for (int t = 0; t < 16; ++t) {
    // ---- stage gathered P rows (each wave: 16 rows, 1KB coalesced per row)
#pragma unroll
    for (int i = 0; i < 16; ++i) {
      int rrow = wave * 16 + i;
      int node = nodeBase + rrow;
      int srow = (node < M) ? src[node * 16 + t] : 0;
      short8 v = *(const short8*)(P + (size_t)srow * 512 + lane * 8);
      *(short8*)(ldsP + rrow * PSTR + lane * 8) = v;
    }
    __syncthreads();  // ldsP(t) ready; ldsH writes of t-1 complete

    // ---- G = h @ Whh^T  ([16,128] @ [128,512] per wave)
#pragma unroll
    for (int nt = 0; nt < 32; ++nt) acc[nt] = zero4;
#pragma unroll
    for (int kt = 0; kt < 4; ++kt) {
      short8 af = *(const short8*)(ldsH + (wave * 16 + nn) * HSTR + kt * 32 + quad * 8);
#pragma unroll
      for (int nt = 0; nt < 32; ++nt) {
        short8 bf = *(const short8*)(Whh + (size_t)(nt * 16 + nn) * HID + kt * 32 + quad * 8);
        acc[nt] = __builtin_amdgcn_mfma_f32_16x16x32_bf16(af, bf, acc[nt], 0, 0, 0);
      }
    }

    // ---- LSTM cell (gate q for col j lives in N-tile nt + 8q, same lane/reg)
#pragma unroll
    for (int nt = 0; nt < 8; ++nt) {
#pragma unroll
      for (int r = 0; r < 4; ++r) {
        int mlocal = wave * 16 + quad * 4 + r;
        const short* pr = ldsP + mlocal * PSTR;
        int col = nt * 16 + nn;
        float ip = acc[nt][r] + bf2f(pr[col]);
        float fp = acc[nt + 8][r] + bf2f(pr[128 + col]);
        float gp = acc[nt + 16][r] + bf2f(pr[256 + col]);
        float op = acc[nt + 24][r] + bf2f(pr[384 + col]);
        float c = sigm(fp) * c_st[nt][r] + sigm(ip) * tanh_(gp);
        c_st[nt][r] = c;
        acc[nt][r] = sigm(op) * tanh_(c);  // reuse acc[0..7] to hold h
      }
    }
    __syncthreads();  // all ldsH(t-1) GEMM reads + ldsP(t) reads done

    // ---- write new h (bf16) for next step's A-fragments
#pragma unroll
    for (int nt = 0; nt < 8; ++nt) {
#pragma unroll
      for (int r = 0; r < 4; ++r) {
        int mlocal = wave * 16 + quad * 4 + r;
        ldsH[mlocal * HSTR + nt * 16 + nn] = f2bf(acc[nt][r]);
      }
    }
  }
  __syncthreads();

  // ---- final h -> aggr, coalesced 16B chunks
  for (int cidx = tid; cidx < NPB * 16; cidx += 128) {
    int rrow = cidx >> 4, off = (cidx & 15) * 8;
    int node = nodeBase + rrow;
    if (node < M) {
      *(short8*)(aggr + (size_t)node * HID + off) = *(const short8*)(ldsH + rrow * HSTR + off);
    }
  }
}

// ---------------- launcher ----------------
extern "C" void kernel_launch(void* const* d_in, const int* in_sizes, int n_in,
                              void* d_out, int out_size, void* d_ws, size_t ws_size,
                              hipStream_t stream) {
  const float* x = (const float*)d_in[0];
  const int* src = (const int*)d_in[1];  // edge_index row 0 = src, first E ints
  const float* Wih[3] = {(const float*)d_in[2], (const float*)d_in[9], (const float*)d_in[16]};
  const float* Whh[3] = {(const float*)d_in[3], (const float*)d_in[10], (const float*)d_in[17]};
  const float* bih[3] = {(const float*)d_in[4], (const float*)d_in[11], (const float*)d_in[18]};
  const float* bhh[3] = {(const float*)d_in[5], (const float*)d_in[12], (const float*)d_in[19]};
  const float* Wl[3]  = {(const float*)d_in[6], (const float*)d_in[13], (const float*)d_in[20]};
  const float* bl[3]  = {(const float*)d_in[7], (const float*)d_in[14], (const float*)d_in[21]};
  const float* Wr[3]  = {(const float*)d_in[8], (const float*)d_in[15], (const float*)d_in[22]};

  const int M = in_sizes[0] / HID;  // 50000

  char* ws = (char*)d_ws;
  size_t off = 0;
  auto alloc = [&](size_t bytes) -> void* {
    void* p = ws + off;
    off += (bytes + 255) & ~(size_t)255;
    return p;
  };
  short* curA = (short*)alloc((size_t)M * HID * 2);
  short* curB = (short*)alloc((size_t)M * HID * 2);
  short* aggr = (short*)alloc((size_t)M * HID * 2);
  short* Pbuf = (short*)alloc((size_t)M * 512 * 2);
  short* wihB = (short*)alloc(512 * HID * 2);
  short* whhB = (short*)alloc(512 * HID * 2);
  short* wlB  = (short*)alloc(HID * HID * 2);
  short* wrB  = (short*)alloc(HID * HID * 2);
  float* bsum = (float*)alloc(512 * 4);

  const int nblk = (M + NPB - 1) / NPB;  // 1563

  conv_x_kernel<<<2048, 256, 0, stream>>>(x, curA, M * HID);

  short* cur = curA;
  short* nxt = curB;
  for (int l = 0; l < 3; ++l) {
    const int Fo = (l == 2) ? 64 : 128;
    conv_layer_kernel<<<256, 256, 0, stream>>>(Wih[l], Whh[l], bih[l], bhh[l], Wl[l], Wr[l],
                                               Fo * HID, wihB, whhB, wlB, wrB, bsum);
    // P = cur @ Wih^T + (bih + bhh)  -> bf16 [M, 512]
    gemm_kernel<32, false, false, false><<<nblk, 128, 0, stream>>>(
        cur, wihB, nullptr, nullptr, bsum, Pbuf, nullptr, M);
    // 16-step LSTM recurrence -> aggr bf16 [M, 128]
    lstm_steps_kernel<<<nblk, 128, 0, stream>>>(Pbuf, whhB, src, aggr, M);
    // out = aggr @ Wl^T + bl + cur @ Wr^T (+ relu)
    if (l < 2) {
      gemm_kernel<8, true, true, false><<<nblk, 128, 0, stream>>>(
          aggr, wlB, cur, wrB, bl[l], nxt, nullptr, M);
      short* tswap = cur; cur = nxt; nxt = tswap;
    } else {
      gemm_kernel<4, true, false, true><<<nblk, 128, 0, stream>>>(
          aggr, wlB, cur, wrB, bl[l], nullptr, (float*)d_out, M);
    }
  }
}

// Round 2
// 1314.109 us; speedup vs baseline: 5.3230x; 5.3230x over previous
//
#include <hip/hip_runtime.h>
#include <cstddef>
#include <cstdint>

typedef __attribute__((ext_vector_type(4))) float f32x4;
typedef __attribute__((ext_vector_type(8))) short short8;

#define HID 128

__device__ __forceinline__ short f2bf(float f) {
  unsigned u = __builtin_bit_cast(unsigned, f);
  u += 0x7FFFu + ((u >> 16) & 1u);
  return (short)(u >> 16);
}
__device__ __forceinline__ float bf2f(short s) {
  unsigned u = ((unsigned)(unsigned short)s) << 16;
  return __builtin_bit_cast(float, u);
}
__device__ __forceinline__ float sigm(float x) {
  return __builtin_amdgcn_rcpf(1.0f + __builtin_amdgcn_exp2f(-1.4426950408889634f * x));
}
__device__ __forceinline__ float tanh_(float x) {
  return 1.0f - 2.0f * __builtin_amdgcn_rcpf(1.0f + __builtin_amdgcn_exp2f(2.8853900817779268f * x));
}

// ---------------- conversion kernels ----------------
__global__ void conv_x_kernel(const float* __restrict__ x, short* __restrict__ xb, int n) {
  int i = blockIdx.x * blockDim.x + threadIdx.x;
  int stride = gridDim.x * blockDim.x;
  for (; i < n; i += stride) xb[i] = f2bf(x[i]);
}

__global__ void conv_layer_kernel(const float* __restrict__ Wih, const float* __restrict__ Whh,
                                  const float* __restrict__ bih, const float* __restrict__ bhh,
                                  const float* __restrict__ Wl, const float* __restrict__ Wr, int foK,
                                  short* __restrict__ wihB, short* __restrict__ whhB,
                                  short* __restrict__ wlB, short* __restrict__ wrB,
                                  float* __restrict__ bsum) {
  int i = blockIdx.x * blockDim.x + threadIdx.x;
  if (i < 512 * HID) { wihB[i] = f2bf(Wih[i]); whhB[i] = f2bf(Whh[i]); }
  if (i < foK) { wlB[i] = f2bf(Wl[i]); wrB[i] = f2bf(Wr[i]); }
  if (i < 512) bsum[i] = bih[i] + bhh[i];
}

// ---------------- generic fused MFMA GEMM ----------------
template <int NTILES, bool HASB2, bool RELU, bool OUTF32>
__global__ __launch_bounds__(128, 2) void gemm_kernel(
    const short* __restrict__ A1, const short* __restrict__ W1,
    const short* __restrict__ A2, const short* __restrict__ W2,
    const float* __restrict__ bias,
    short* __restrict__ outB, float* __restrict__ outF, int M) {
  const int NC = NTILES * 16;
  const int tid = threadIdx.x;
  const int wave = tid >> 6, lane = tid & 63;
  const int quad = lane >> 4, nn = lane & 15;
  const int row0 = blockIdx.x * 32 + wave * 16;
  int arow = row0 + nn;
  if (arow > M - 1) arow = M - 1;

  const f32x4 zero4 = {0.f, 0.f, 0.f, 0.f};
  f32x4 acc[NTILES];
#pragma unroll
  for (int i = 0; i < NTILES; ++i) acc[i] = zero4;

#pragma unroll
  for (int kt = 0; kt < 4; ++kt) {
    short8 af = *(const short8*)(A1 + (size_t)arow * HID + kt * 32 + quad * 8);
#pragma unroll
    for (int nt = 0; nt < NTILES; ++nt) {
      short8 bf = *(const short8*)(W1 + (size_t)(nt * 16 + nn) * HID + kt * 32 + quad * 8);
      acc[nt] = __builtin_amdgcn_mfma_f32_16x16x32_bf16(af, bf, acc[nt], 0, 0, 0);
    }
  }
  if (HASB2) {
#pragma unroll
    for (int kt = 0; kt < 4; ++kt) {
      short8 af = *(const short8*)(A2 + (size_t)arow * HID + kt * 32 + quad * 8);
#pragma unroll
      for (int nt = 0; nt < NTILES; ++nt) {
        short8 bf = *(const short8*)(W2 + (size_t)(nt * 16 + nn) * HID + kt * 32 + quad * 8);
        acc[nt] = __builtin_amdgcn_mfma_f32_16x16x32_bf16(af, bf, acc[nt], 0, 0, 0);
      }
    }
  }
#pragma unroll
  for (int nt = 0; nt < NTILES; ++nt) {
    int col = nt * 16 + nn;
    float b = bias[col];
#pragma unroll
    for (int r = 0; r < 4; ++r) {
      int m = row0 + quad * 4 + r;
      if (m < M) {
        float v = acc[nt][r] + b;
        if (RELU) v = fmaxf(v, 0.0f);
        if (OUTF32) outF[(size_t)m * NC + col] = v;
        else outB[(size_t)m * NC + col] = f2bf(v);
      }
    }
  }
}

// ---------------- persistent LSTM recurrence, gate-split waves ----------------
// Block = 256 threads (4 waves), 32 nodes. Wave q holds gate-q's Whh chunk
// [128x128] in 128 VGPRs (loaded once) -> ZERO weight traffic in the step
// loop. Per step: async gather P rows via global_load_lds (hidden behind
// MFMA), G = h@Whh_q^T (64 MFMA, weights from regs), exchange G through LDS
// (bf16), cell phase row-split across all 256 threads, h back to LDS.
#define NPB 32
#define PSTR 520  // 512 + 8 pad
#define GSTR 520
#define HSTR 136  // 128 + 8 pad
#define LSTM_LDS_BYTES ((NPB * PSTR + NPB * GSTR + NPB * HSTR) * 2 + NPB * 16 * 4)  // 77312

__global__ __launch_bounds__(256, 2) void lstm_steps_kernel(
    const short* __restrict__ P, const short* __restrict__ Whh,
    const int* __restrict__ src, short* __restrict__ aggr, int M) {
  extern __shared__ char smem[];
  short* ldsP = (short*)smem;            // [32][520]
  short* ldsG = ldsP + NPB * PSTR;       // [32][520] (512 gate cols used)
  short* ldsH = ldsG + NPB * GSTR;       // [32][136]
  int* srcL = (int*)(ldsH + NPB * HSTR); // [32*16]

  const int tid = threadIdx.x;
  const int wave = tid >> 6, lane = tid & 63;
  const int quad = lane >> 4, nn = lane & 15;
  const int nodeBase = blockIdx.x * NPB;

  // ---- Whh fragments for this wave's gate chunk (cols [wave*128, +128)) ----
  short8 wreg[4][8];
#pragma unroll
  for (int kt = 0; kt < 4; ++kt)
#pragma unroll
    for (int nt = 0; nt < 8; ++nt)
      wreg[kt][nt] = *(const short8*)(Whh + (size_t)(wave * 128 + nt * 16 + nn) * HID + kt * 32 + quad * 8);

  // ---- preload src indices, zero h0 ----
  for (int i = tid; i < NPB * 16; i += 256) {
    int node = nodeBase + (i >> 4);
    srcL[i] = (node < M) ? src[nodeBase * 16 + i] : 0;
  }
  for (int i = tid; i < NPB * HSTR; i += 256) ldsH[i] = 0;

  float c_st[16];
#pragma unroll
  for (int i = 0; i < 16; ++i) c_st[i] = 0.f;

  const int crow = tid >> 3;        // cell row 0..31
  const int ccol = (tid & 7) * 16;  // cell col base (16 cols per thread)

  __syncthreads();

  const f32x4 zero4 = {0.f, 0.f, 0.f, 0.f};

#pragma unroll 1
  for (int t = 0; t < 16; ++t) {
    // ---- async gather: 8 rows/wave, direct global->LDS (no VGPR staging).
    // LDS dest = wave-uniform row base + lane*16B (contiguous 1KB row). ----
#pragma unroll
    for (int i = 0; i < 8; ++i) {
      int rrow = wave * 8 + i;
      int srow = srcL[rrow * 16 + t];
      __builtin_amdgcn_global_load_lds(
          (const __attribute__((address_space(1))) unsigned int*)(P + (size_t)srow * 512 + lane * 8),
          (__attribute__((address_space(3))) unsigned int*)(ldsP + rrow * PSTR),
          16, 0, 0);
    }

    // ---- G = h(t-1) @ Whh_q^T : weights from registers ----
    f32x4 acc[2][8];
#pragma unroll
    for (int m = 0; m < 2; ++m)
#pragma unroll
      for (int nt = 0; nt < 8; ++nt) acc[m][nt] = zero4;
#pragma unroll
    for (int kt = 0; kt < 4; ++kt) {
      short8 af0 = *(const short8*)(ldsH + (0 * 16 + nn) * HSTR + kt * 32 + quad * 8);
      short8 af1 = *(const short8*)(ldsH + (1 * 16 + nn) * HSTR + kt * 32 + quad * 8);
#pragma unroll
      for (int nt = 0; nt < 8; ++nt) {
        acc[0][nt] = __builtin_amdgcn_mfma_f32_16x16x32_bf16(af0, wreg[kt][nt], acc[0][nt], 0, 0, 0);
        acc[1][nt] = __builtin_amdgcn_mfma_f32_16x16x32_bf16(af1, wreg[kt][nt], acc[1][nt], 0, 0, 0);
      }
    }

    // ---- exchange: write G (bf16) to LDS in (row, gatecol) layout ----
#pragma unroll
    for (int m = 0; m < 2; ++m)
#pragma unroll
      for (int nt = 0; nt < 8; ++nt)
#pragma unroll
        for (int r = 0; r < 4; ++r)
          ldsG[(m * 16 + quad * 4 + r) * GSTR + wave * 128 + nt * 16 + nn] = f2bf(acc[m][nt][r]);

    __syncthreads();  // G ready; vmcnt drain => ldsP(t) ready

    // ---- LSTM cell: thread owns (crow, ccol..ccol+15), all 4 gates ----
    const short* gRow = ldsG + crow * GSTR;
    const short* pRow = ldsP + crow * PSTR;
#pragma unroll
    for (int h = 0; h < 2; ++h) {
      short8 vi = *(const short8*)(gRow + 0 * 128 + ccol + h * 8);
      short8 vf = *(const short8*)(gRow + 1 * 128 + ccol + h * 8);
      short8 vg = *(const short8*)(gRow + 2 * 128 + ccol + h * 8);
      short8 vo = *(const short8*)(gRow + 3 * 128 + ccol + h * 8);
      short8 pi = *(const short8*)(pRow + 0 * 128 + ccol + h * 8);
      short8 pf = *(const short8*)(pRow + 1 * 128 + ccol + h * 8);
      short8 pg = *(const short8*)(pRow + 2 * 128 + ccol + h * 8);
      short8 po = *(const short8*)(pRow + 3 * 128 + ccol + h * 8);
      short8 hh;
#pragma unroll
      for (int j = 0; j < 8; ++j) {
        float ip = bf2f(vi[j]) + bf2f(pi[j]);
        float fp = bf2f(vf[j]) + bf2f(pf[j]);
        float gp = bf2f(vg[j]) + bf2f(pg[j]);
        float op = bf2f(vo[j]) + bf2f(po[j]);
        float c = sigm(fp) * c_st[h * 8 + j] + sigm(ip) * tanh_(gp);
        c_st[h * 8 + j] = c;
        hh[j] = f2bf(sigm(op) * tanh_(c));
      }
      *(short8*)(ldsH + crow * HSTR + ccol + h * 8) = hh;
    }
    __syncthreads();  // h(t) ready; ldsP/ldsG reads done before next overwrite
  }

  // ---- final h -> aggr ----
  for (int cidx = tid; cidx < NPB * 16; cidx += 256) {
    int rrow = cidx >> 4, off = (cidx & 15) * 8;
    int node = nodeBase + rrow;
    if (node < M) {
      *(short8*)(aggr + (size_t)node * HID + off) = *(const short8*)(ldsH + rrow * HSTR + off);
    }
  }
}

// ---------------- launcher ----------------
extern "C" void kernel_launch(void* const* d_in, const int* in_sizes, int n_in,
                              void* d_out, int out_size, void* d_ws, size_t ws_size,
                              hipStream_t stream) {
  const float* x = (const float*)d_in[0];
  const int* src = (const int*)d_in[1];
  const float* Wih[3] = {(const float*)d_in[2], (const float*)d_in[9], (const float*)d_in[16]};
  const float* Whh[3] = {(const float*)d_in[3], (const float*)d_in[10], (const float*)d_in[17]};
  const float* bih[3] = {(const float*)d_in[4], (const float*)d_in[11], (const float*)d_in[18]};
  const float* bhh[3] = {(const float*)d_in[5], (const float*)d_in[12], (const float*)d_in[19]};
  const float* Wl[3]  = {(const float*)d_in[6], (const float*)d_in[13], (const float*)d_in[20]};
  const float* bl[3]  = {(const float*)d_in[7], (const float*)d_in[14], (const float*)d_in[21]};
  const float* Wr[3]  = {(const float*)d_in[8], (const float*)d_in[15], (const float*)d_in[22]};

  const int M = in_sizes[0] / HID;  // 50000

  char* ws = (char*)d_ws;
  size_t off = 0;
  auto alloc = [&](size_t bytes) -> void* {
    void* p = ws + off;
    off += (bytes + 255) & ~(size_t)255;
    return p;
  };
  short* curA = (short*)alloc((size_t)M * HID * 2);
  short* curB = (short*)alloc((size_t)M * HID * 2);
  short* aggr = (short*)alloc((size_t)M * HID * 2);
  short* Pbuf = (short*)alloc((size_t)M * 512 * 2);
  short* wihB = (short*)alloc(512 * HID * 2);
  short* whhB = (short*)alloc(512 * HID * 2);
  short* wlB  = (short*)alloc(HID * HID * 2);
  short* wrB  = (short*)alloc(HID * HID * 2);
  float* bsum = (float*)alloc(512 * 4);

  const int nblk = (M + NPB - 1) / NPB;  // 1563

  // allow >64KB dynamic LDS for the lstm kernel (idempotent; safe under capture)
  (void)hipFuncSetAttribute((const void*)lstm_steps_kernel,
                            hipFuncAttributeMaxDynamicSharedMemorySize, LSTM_LDS_BYTES);

  conv_x_kernel<<<2048, 256, 0, stream>>>(x, curA, M * HID);

  short* cur = curA;
  short* nxt = curB;
  for (int l = 0; l < 3; ++l) {
    const int Fo = (l == 2) ? 64 : 128;
    conv_layer_kernel<<<256, 256, 0, stream>>>(Wih[l], Whh[l], bih[l], bhh[l], Wl[l], Wr[l],
                                               Fo * HID, wihB, whhB, wlB, wrB, bsum);
    gemm_kernel<32, false, false, false><<<nblk, 128, 0, stream>>>(
        cur, wihB, nullptr, nullptr, bsum, Pbuf, nullptr, M);
    lstm_steps_kernel<<<nblk, 256, LSTM_LDS_BYTES, stream>>>(Pbuf, whhB, src, aggr, M);
    if (l < 2) {
      gemm_kernel<8, true, true, false><<<nblk, 128, 0, stream>>>(
          aggr, wlB, cur, wrB, bl[l], nxt, nullptr, M);
      short* tswap = cur; cur = nxt; nxt = tswap;
    } else {
      gemm_kernel<4, true, false, true><<<nblk, 128, 0, stream>>>(
          aggr, wlB, cur, wrB, bl[l], nullptr, (float*)d_out, M);
    }
  }
}

// Round 3
// 1099.582 us; speedup vs baseline: 6.3615x; 1.1951x over previous
//
#include <hip/hip_runtime.h>
#include <cstddef>
#include <cstdint>

typedef __attribute__((ext_vector_type(4))) float f32x4;
typedef __attribute__((ext_vector_type(8))) short short8;

#define HID 128

// LDS-only barrier: no vmcnt(0) drain (gathers stay in flight across it).
#define BAR_LGKM() __asm__ volatile("s_waitcnt lgkmcnt(0)\ns_barrier" ::: "memory")
#define WAIT_VM0() __asm__ volatile("s_waitcnt vmcnt(0)" ::: "memory")

__device__ __forceinline__ short f2bf(float f) {
  unsigned u = __builtin_bit_cast(unsigned, f);
  u += 0x7FFFu + ((u >> 16) & 1u);
  return (short)(u >> 16);
}
__device__ __forceinline__ float bf2f(short s) {
  unsigned u = ((unsigned)(unsigned short)s) << 16;
  return __builtin_bit_cast(float, u);
}
__device__ __forceinline__ float sigm(float x) {
  return __builtin_amdgcn_rcpf(1.0f + __builtin_amdgcn_exp2f(-1.4426950408889634f * x));
}
__device__ __forceinline__ float tanh_(float x) {
  return 1.0f - 2.0f * __builtin_amdgcn_rcpf(1.0f + __builtin_amdgcn_exp2f(2.8853900817779268f * x));
}

// ---------------- conversion kernels ----------------
__global__ void conv_x_kernel(const float* __restrict__ x, short* __restrict__ xb, int n) {
  int i = blockIdx.x * blockDim.x + threadIdx.x;
  int stride = gridDim.x * blockDim.x;
  for (; i < n; i += stride) xb[i] = f2bf(x[i]);
}

__global__ void conv_layer_kernel(const float* __restrict__ Wih, const float* __restrict__ Whh,
                                  const float* __restrict__ bih, const float* __restrict__ bhh,
                                  const float* __restrict__ Wl, const float* __restrict__ Wr, int foK,
                                  short* __restrict__ wihB, short* __restrict__ whhB,
                                  short* __restrict__ wlB, short* __restrict__ wrB,
                                  float* __restrict__ bsum) {
  int i = blockIdx.x * blockDim.x + threadIdx.x;
  if (i < 512 * HID) { wihB[i] = f2bf(Wih[i]); whhB[i] = f2bf(Whh[i]); }
  if (i < foK) { wlB[i] = f2bf(Wl[i]); wrB[i] = f2bf(Wr[i]); }
  if (i < 512) bsum[i] = bih[i] + bhh[i];
}

// ---------------- persistent P-GEMM: P = A @ Wih^T + bias -> bf16 [M,512] ----
// 256 thr = 4 waves; wave q holds Wih cols [q*128,+128) in 128 VGPRs. Grid-
// stride over 32-row tiles; LDS-bounce epilogue -> fully coalesced b128 stores.
#define OSTR 520
__global__ __launch_bounds__(256, 2) void pgemm_kernel(
    const short* __restrict__ A, const short* __restrict__ W,
    const float* __restrict__ bias, short* __restrict__ out, int M, int ntiles) {
  __shared__ short ldsO[32 * OSTR];  // 33.3 KB
  const int tid = threadIdx.x;
  const int wave = tid >> 6, lane = tid & 63;
  const int quad = lane >> 4, nn = lane & 15;

  short8 wreg[4][8];
#pragma unroll
  for (int kt = 0; kt < 4; ++kt)
#pragma unroll
    for (int nt = 0; nt < 8; ++nt)
      wreg[kt][nt] = *(const short8*)(W + (size_t)(wave * 128 + nt * 16 + nn) * HID + kt * 32 + quad * 8);
  float bfr[8];
#pragma unroll
  for (int nt = 0; nt < 8; ++nt) bfr[nt] = bias[wave * 128 + nt * 16 + nn];

  const f32x4 zero4 = {0.f, 0.f, 0.f, 0.f};
#pragma unroll 1
  for (int rt = blockIdx.x; rt < ntiles; rt += gridDim.x) {
    const int row0 = rt * 32;
    f32x4 acc[2][8];
#pragma unroll
    for (int m = 0; m < 2; ++m)
#pragma unroll
      for (int nt = 0; nt < 8; ++nt) acc[m][nt] = zero4;
#pragma unroll
    for (int kt = 0; kt < 4; ++kt) {
      int r0 = row0 + nn;          if (r0 > M - 1) r0 = M - 1;
      int r1 = row0 + 16 + nn;     if (r1 > M - 1) r1 = M - 1;
      short8 af0 = *(const short8*)(A + (size_t)r0 * HID + kt * 32 + quad * 8);
      short8 af1 = *(const short8*)(A + (size_t)r1 * HID + kt * 32 + quad * 8);
#pragma unroll
      for (int nt = 0; nt < 8; ++nt) {
        acc[0][nt] = __builtin_amdgcn_mfma_f32_16x16x32_bf16(af0, wreg[kt][nt], acc[0][nt], 0, 0, 0);
        acc[1][nt] = __builtin_amdgcn_mfma_f32_16x16x32_bf16(af1, wreg[kt][nt], acc[1][nt], 0, 0, 0);
      }
    }
    BAR_LGKM();  // previous iteration's ldsO reads complete
#pragma unroll
    for (int m = 0; m < 2; ++m)
#pragma unroll
      for (int nt = 0; nt < 8; ++nt)
#pragma unroll
        for (int r = 0; r < 4; ++r)
          ldsO[(m * 16 + quad * 4 + r) * OSTR + wave * 128 + nt * 16 + nn] = f2bf(acc[m][nt][r] + bfr[nt]);
    BAR_LGKM();
#pragma unroll
    for (int idx = tid; idx < 32 * 64; idx += 256) {
      int row = idx >> 6, c8 = (idx & 63) * 8;
      if (row0 + row < M)
        *(short8*)(out + (size_t)(row0 + row) * 512 + c8) = *(const short8*)(ldsO + row * OSTR + c8);
    }
  }
}

// ---------------- fused output GEMM: out = A1@W1^T + bias + A2@W2^T ----------
// FO=128 (relu, bf16 out) or FO=64 (f32 out). Wave q owns cols [q*FO/4,+FO/4).
template <int FO, bool RELU, bool OUTF32>
__global__ __launch_bounds__(256, 4) void outgemm_kernel(
    const short* __restrict__ A1, const short* __restrict__ W1,
    const short* __restrict__ A2, const short* __restrict__ W2,
    const float* __restrict__ bias,
    short* __restrict__ outB, float* __restrict__ outF, int M) {
  const int NTW = FO / 64;  // n-tiles per wave
  __shared__ char osm[8704];
  short* ldsO = (short*)osm;   // [32][136] when bf16 out
  float* ldsF = (float*)osm;   // [32][68]  when f32 out
  const int tid = threadIdx.x;
  const int wave = tid >> 6, lane = tid & 63;
  const int quad = lane >> 4, nn = lane & 15;
  const int cbase = wave * (FO / 4);
  const int row0 = blockIdx.x * 32;

  short8 w1r[4][NTW], w2r[4][NTW];
#pragma unroll
  for (int kt = 0; kt < 4; ++kt)
#pragma unroll
    for (int nt = 0; nt < NTW; ++nt) {
      w1r[kt][nt] = *(const short8*)(W1 + (size_t)(cbase + nt * 16 + nn) * HID + kt * 32 + quad * 8);
      w2r[kt][nt] = *(const short8*)(W2 + (size_t)(cbase + nt * 16 + nn) * HID + kt * 32 + quad * 8);
    }
  float bfr[NTW];
#pragma unroll
  for (int nt = 0; nt < NTW; ++nt) bfr[nt] = bias[cbase + nt * 16 + nn];

  const f32x4 zero4 = {0.f, 0.f, 0.f, 0.f};
  f32x4 acc[2][NTW];
#pragma unroll
  for (int m = 0; m < 2; ++m)
#pragma unroll
    for (int nt = 0; nt < NTW; ++nt) acc[m][nt] = zero4;

#pragma unroll
  for (int kt = 0; kt < 4; ++kt) {
    int r0 = row0 + nn;      if (r0 > M - 1) r0 = M - 1;
    int r1 = row0 + 16 + nn; if (r1 > M - 1) r1 = M - 1;
    short8 a10 = *(const short8*)(A1 + (size_t)r0 * HID + kt * 32 + quad * 8);
    short8 a11 = *(const short8*)(A1 + (size_t)r1 * HID + kt * 32 + quad * 8);
    short8 a20 = *(const short8*)(A2 + (size_t)r0 * HID + kt * 32 + quad * 8);
    short8 a21 = *(const short8*)(A2 + (size_t)r1 * HID + kt * 32 + quad * 8);
#pragma unroll
    for (int nt = 0; nt < NTW; ++nt) {
      acc[0][nt] = __builtin_amdgcn_mfma_f32_16x16x32_bf16(a10, w1r[kt][nt], acc[0][nt], 0, 0, 0);
      acc[1][nt] = __builtin_amdgcn_mfma_f32_16x16x32_bf16(a11, w1r[kt][nt], acc[1][nt], 0, 0, 0);
      acc[0][nt] = __builtin_amdgcn_mfma_f32_16x16x32_bf16(a20, w2r[kt][nt], acc[0][nt], 0, 0, 0);
      acc[1][nt] = __builtin_amdgcn_mfma_f32_16x16x32_bf16(a21, w2r[kt][nt], acc[1][nt], 0, 0, 0);
    }
  }
#pragma unroll
  for (int m = 0; m < 2; ++m)
#pragma unroll
    for (int nt = 0; nt < NTW; ++nt)
#pragma unroll
      for (int r = 0; r < 4; ++r) {
        float v = acc[m][nt][r] + bfr[nt];
        if (RELU) v = fmaxf(v, 0.0f);
        int lrow = m * 16 + quad * 4 + r;
        if (OUTF32) ldsF[lrow * 68 + cbase + nt * 16 + nn] = v;
        else        ldsO[lrow * 136 + cbase + nt * 16 + nn] = f2bf(v);
      }
  BAR_LGKM();
  if (OUTF32) {
#pragma unroll
    for (int idx = tid; idx < 32 * 16; idx += 256) {
      int row = idx >> 4, c4 = (idx & 15) * 4;
      if (row0 + row < M)
        *(f32x4*)(outF + (size_t)(row0 + row) * 64 + c4) = *(const f32x4*)(ldsF + row * 68 + c4);
    }
  } else {
#pragma unroll
    for (int idx = tid; idx < 32 * 16; idx += 256) {
      int row = idx >> 4, c8 = (idx & 15) * 8;
      if (row0 + row < M)
        *(short8*)(outB + (size_t)(row0 + row) * 128 + c8) = *(const short8*)(ldsO + row * 136 + c8);
    }
  }
}

// ---------------- persistent LSTM recurrence, gate-split waves ----------------
// Gathers are wave-self-consumed (wave w gathers & reads ldsP rows [8w,8w+8)),
// so barriers are LDS-only (no vmcnt drain) and gather(t+1) is issued inside
// cell(t) right after this wave's own P-reads -> ~full-step latency cover.
#define NPB 32
#define PSTR 520
#define GSTR 520
#define HSTR 136
#define LSTM_LDS_BYTES ((NPB * PSTR + NPB * GSTR + NPB * HSTR) * 2 + NPB * 16 * 4)  // 77312

__global__ __launch_bounds__(256, 2) void lstm_steps_kernel(
    const short* __restrict__ P, const short* __restrict__ Whh,
    const int* __restrict__ src, short* __restrict__ aggr, int M) {
  extern __shared__ char smem[];
  short* ldsP = (short*)smem;
  short* ldsG = ldsP + NPB * PSTR;
  short* ldsH = ldsG + NPB * GSTR;
  int* srcL = (int*)(ldsH + NPB * HSTR);

  const int tid = threadIdx.x;
  const int wave = tid >> 6, lane = tid & 63;
  const int quad = lane >> 4, nn = lane & 15;
  const int nodeBase = blockIdx.x * NPB;

  short8 wreg[4][8];
#pragma unroll
  for (int kt = 0; kt < 4; ++kt)
#pragma unroll
    for (int nt = 0; nt < 8; ++nt)
      wreg[kt][nt] = *(const short8*)(Whh + (size_t)(wave * 128 + nt * 16 + nn) * HID + kt * 32 + quad * 8);

  for (int i = tid; i < NPB * 16; i += 256) {
    int node = nodeBase + (i >> 4);
    srcL[i] = (node < M) ? src[nodeBase * 16 + i] : 0;
  }
  for (int i = tid; i < NPB * HSTR; i += 256) ldsH[i] = 0;

  float c_st[16];
#pragma unroll
  for (int i = 0; i < 16; ++i) c_st[i] = 0.f;

  const int crow = tid >> 3;        // cell row 0..31 (wave w -> rows [8w,8w+8))
  const int ccol = (tid & 7) * 16;  // 16 cols per thread

  __syncthreads();  // srcL/ldsH init visible (full drain OK here, once)

  // prologue: gather for t=0 (wave's own 8 rows)
#pragma unroll
  for (int i = 0; i < 8; ++i) {
    int rrow = wave * 8 + i;
    int srow = srcL[rrow * 16 + 0];
    __builtin_amdgcn_global_load_lds(
        (const __attribute__((address_space(1))) unsigned int*)(P + (size_t)srow * 512 + lane * 8),
        (__attribute__((address_space(3))) unsigned int*)(ldsP + rrow * PSTR), 16, 0, 0);
  }

  const f32x4 zero4 = {0.f, 0.f, 0.f, 0.f};

#pragma unroll 1
  for (int t = 0; t < 16; ++t) {
    // ---- G = h(t-1) @ Whh_q^T (weights in regs) ----
    f32x4 acc[2][8];
#pragma unroll
    for (int m = 0; m < 2; ++m)
#pragma unroll
      for (int nt = 0; nt < 8; ++nt) acc[m][nt] = zero4;
#pragma unroll
    for (int kt = 0; kt < 4; ++kt) {
      short8 af0 = *(const short8*)(ldsH + (0 * 16 + nn) * HSTR + kt * 32 + quad * 8);
      short8 af1 = *(const short8*)(ldsH + (1 * 16 + nn) * HSTR + kt * 32 + quad * 8);
#pragma unroll
      for (int nt = 0; nt < 8; ++nt) {
        acc[0][nt] = __builtin_amdgcn_mfma_f32_16x16x32_bf16(af0, wreg[kt][nt], acc[0][nt], 0, 0, 0);
        acc[1][nt] = __builtin_amdgcn_mfma_f32_16x16x32_bf16(af1, wreg[kt][nt], acc[1][nt], 0, 0, 0);
      }
    }
    // ---- exchange G (bf16) ----
#pragma unroll
    for (int m = 0; m < 2; ++m)
#pragma unroll
      for (int nt = 0; nt < 8; ++nt)
#pragma unroll
        for (int r = 0; r < 4; ++r)
          ldsG[(m * 16 + quad * 4 + r) * GSTR + wave * 128 + nt * 16 + nn] = f2bf(acc[m][nt][r]);

    BAR_LGKM();  // ldsG visible; ldsH reads done (no vmcnt drain)
    WAIT_VM0();  // this wave's gather(t) has landed in its ldsP rows

    const short* gRow = ldsG + crow * GSTR;
    const short* pRow = ldsP + crow * PSTR;
    short* hRow = ldsH + crow * HSTR;

    // ---- cell, first 8 cols ----
    {
      short8 vi = *(const short8*)(gRow + 0 * 128 + ccol);
      short8 vf = *(const short8*)(gRow + 1 * 128 + ccol);
      short8 vg = *(const short8*)(gRow + 2 * 128 + ccol);
      short8 vo = *(const short8*)(gRow + 3 * 128 + ccol);
      short8 pi = *(const short8*)(pRow + 0 * 128 + ccol);
      short8 pf = *(const short8*)(pRow + 1 * 128 + ccol);
      short8 pg = *(const short8*)(pRow + 2 * 128 + ccol);
      short8 po = *(const short8*)(pRow + 3 * 128 + ccol);
      short8 hh;
#pragma unroll
      for (int j = 0; j < 8; ++j) {
        float ip = bf2f(vi[j]) + bf2f(pi[j]);
        float fp = bf2f(vf[j]) + bf2f(pf[j]);
        float gp = bf2f(vg[j]) + bf2f(pg[j]);
        float op = bf2f(vo[j]) + bf2f(po[j]);
        float c = sigm(fp) * c_st[j] + sigm(ip) * tanh_(gp);
        c_st[j] = c;
        hh[j] = f2bf(sigm(op) * tanh_(c));
      }
      *(short8*)(hRow + ccol) = hh;
    }
    // ---- cell, second 8 cols: read P first, then prefetch next gather ----
    short8 vi = *(const short8*)(gRow + 0 * 128 + ccol + 8);
    short8 vf = *(const short8*)(gRow + 1 * 128 + ccol + 8);
    short8 vg = *(const short8*)(gRow + 2 * 128 + ccol + 8);
    short8 vo = *(const short8*)(gRow + 3 * 128 + ccol + 8);
    short8 pi = *(const short8*)(pRow + 0 * 128 + ccol + 8);
    short8 pf = *(const short8*)(pRow + 1 * 128 + ccol + 8);
    short8 pg = *(const short8*)(pRow + 2 * 128 + ccol + 8);
    short8 po = *(const short8*)(pRow + 3 * 128 + ccol + 8);

    // all of this wave's ldsP(t) reads are now issued -> safe to overwrite
    // its own rows with gather(t+1); covered by cell math + 2 phases.
    if (t < 15) {
#pragma unroll
      for (int i = 0; i < 8; ++i) {
        int rrow = wave * 8 + i;
        int srow = srcL[rrow * 16 + t + 1];
        __builtin_amdgcn_global_load_lds(
            (const __attribute__((address_space(1))) unsigned int*)(P + (size_t)srow * 512 + lane * 8),
            (__attribute__((address_space(3))) unsigned int*)(ldsP + rrow * PSTR), 16, 0, 0);
      }
    }
    {
      short8 hh;
#pragma unroll
      for (int j = 0; j < 8; ++j) {
        float ip = bf2f(vi[j]) + bf2f(pi[j]);
        float fp = bf2f(vf[j]) + bf2f(pf[j]);
        float gp = bf2f(vg[j]) + bf2f(pg[j]);
        float op = bf2f(vo[j]) + bf2f(po[j]);
        float c = sigm(fp) * c_st[8 + j] + sigm(ip) * tanh_(gp);
        c_st[8 + j] = c;
        hh[j] = f2bf(sigm(op) * tanh_(c));
      }
      *(short8*)(hRow + ccol + 8) = hh;
    }
    BAR_LGKM();  // h(t) visible for next step's MFMA; ldsG reads done
  }

  // ---- final h -> aggr ----
  for (int cidx = tid; cidx < NPB * 16; cidx += 256) {
    int rrow = cidx >> 4, off = (cidx & 15) * 8;
    int node = nodeBase + rrow;
    if (node < M) {
      *(short8*)(aggr + (size_t)node * HID + off) = *(const short8*)(ldsH + rrow * HSTR + off);
    }
  }
}

// ---------------- launcher ----------------
extern "C" void kernel_launch(void* const* d_in, const int* in_sizes, int n_in,
                              void* d_out, int out_size, void* d_ws, size_t ws_size,
                              hipStream_t stream) {
  const float* x = (const float*)d_in[0];
  const int* src = (const int*)d_in[1];
  const float* Wih[3] = {(const float*)d_in[2], (const float*)d_in[9], (const float*)d_in[16]};
  const float* Whh[3] = {(const float*)d_in[3], (const float*)d_in[10], (const float*)d_in[17]};
  const float* bih[3] = {(const float*)d_in[4], (const float*)d_in[11], (const float*)d_in[18]};
  const float* bhh[3] = {(const float*)d_in[5], (const float*)d_in[12], (const float*)d_in[19]};
  const float* Wl[3]  = {(const float*)d_in[6], (const float*)d_in[13], (const float*)d_in[20]};
  const float* bl[3]  = {(const float*)d_in[7], (const float*)d_in[14], (const float*)d_in[21]};
  const float* Wr[3]  = {(const float*)d_in[8], (const float*)d_in[15], (const float*)d_in[22]};

  const int M = in_sizes[0] / HID;  // 50000

  char* ws = (char*)d_ws;
  size_t off = 0;
  auto alloc = [&](size_t bytes) -> void* {
    void* p = ws + off;
    off += (bytes + 255) & ~(size_t)255;
    return p;
  };
  short* curA = (short*)alloc((size_t)M * HID * 2);
  short* curB = (short*)alloc((size_t)M * HID * 2);
  short* aggr = (short*)alloc((size_t)M * HID * 2);
  short* Pbuf = (short*)alloc((size_t)M * 512 * 2);
  short* wihB = (short*)alloc(512 * HID * 2);
  short* whhB = (short*)alloc(512 * HID * 2);
  short* wlB  = (short*)alloc(HID * HID * 2);
  short* wrB  = (short*)alloc(HID * HID * 2);
  float* bsum = (float*)alloc(512 * 4);

  const int nblk = (M + NPB - 1) / NPB;   // 1563
  const int ntiles = (M + 31) / 32;       // 1563

  (void)hipFuncSetAttribute((const void*)lstm_steps_kernel,
                            hipFuncAttributeMaxDynamicSharedMemorySize, LSTM_LDS_BYTES);

  conv_x_kernel<<<2048, 256, 0, stream>>>(x, curA, M * HID);

  short* cur = curA;
  short* nxt = curB;
  for (int l = 0; l < 3; ++l) {
    const int Fo = (l == 2) ? 64 : 128;
    conv_layer_kernel<<<256, 256, 0, stream>>>(Wih[l], Whh[l], bih[l], bhh[l], Wl[l], Wr[l],
                                               Fo * HID, wihB, whhB, wlB, wrB, bsum);
    pgemm_kernel<<<512, 256, 0, stream>>>(cur, wihB, bsum, Pbuf, M, ntiles);
    lstm_steps_kernel<<<nblk, 256, LSTM_LDS_BYTES, stream>>>(Pbuf, whhB, src, aggr, M);
    if (l < 2) {
      outgemm_kernel<128, true, false><<<ntiles, 256, 0, stream>>>(
          aggr, wlB, cur, wrB, bl[l], nxt, nullptr, M);
      short* tswap = cur; cur = nxt; nxt = tswap;
    } else {
      outgemm_kernel<64, false, true><<<ntiles, 256, 0, stream>>>(
          aggr, wlB, cur, wrB, bl[l], nullptr, (float*)d_out, M);
    }
  }
}

// Round 4
// 1083.919 us; speedup vs baseline: 6.4534x; 1.0145x over previous
//
#include <hip/hip_runtime.h>
#include <cstddef>
#include <cstdint>

typedef __attribute__((ext_vector_type(4))) float f32x4;
typedef __attribute__((ext_vector_type(8))) short short8;
typedef __attribute__((ext_vector_type(4))) int int4v;

#define HID 128
#define NK1 -1.4426950408889634f  // -log2(e)
#define PK2 2.8853900817779268f   // +2*log2(e)

// LDS-only barrier: no vmcnt(0) drain (gathers stay in flight across it).
#define BAR_LGKM() __asm__ volatile("s_waitcnt lgkmcnt(0)\ns_barrier" ::: "memory")
#define WAIT_VM0() __asm__ volatile("s_waitcnt vmcnt(0)" ::: "memory")
#define WAIT_LGKM() __asm__ volatile("s_waitcnt lgkmcnt(0)" ::: "memory")

__device__ __forceinline__ short f2bf(float f) {
  unsigned u = __builtin_bit_cast(unsigned, f);
  u += 0x7FFFu + ((u >> 16) & 1u);
  return (short)(u >> 16);
}
// pack two f32 -> two bf16 (round-half-up) in one u32 via v_perm
__device__ __forceinline__ unsigned pack_bf2(float a, float b) {
  unsigned ua = __builtin_bit_cast(unsigned, a) + 0x8000u;
  unsigned ub = __builtin_bit_cast(unsigned, b) + 0x8000u;
  return __builtin_amdgcn_perm(ub, ua, 0x07060302u);
}
__device__ __forceinline__ void unpack2(int w, float& lo, float& hi) {
  lo = __builtin_bit_cast(float, (unsigned)(w << 16));
  hi = __builtin_bit_cast(float, (unsigned)w & 0xffff0000u);
}

// folded LSTM cell: inputs are PRE-SCALED pre-activations
// si,sf,so = -log2e*(gate), sg = 2log2e*(g). 5 exp2 + 2 rcp.
__device__ __forceinline__ float lstm_elem(float si, float sf, float sg, float so, float& c) {
  float Ei = __builtin_amdgcn_exp2f(si);
  float Ef = __builtin_amdgcn_exp2f(sf);
  float Tg = __builtin_amdgcn_exp2f(sg);
  float Eo = __builtin_amdgcn_exp2f(so);
  float u = 1.0f + Ei, w = 1.0f + Ef, v = Tg + 1.0f, Tm = Tg - 1.0f;
  float t0 = u * v;
  float num = __builtin_fmaf(c, t0, w * Tm);
  float cn = num * __builtin_amdgcn_rcpf(w * t0);
  c = cn;
  float Tc = __builtin_amdgcn_exp2f(PK2 * cn);
  return (Tc - 1.0f) * __builtin_amdgcn_rcpf((1.0f + Eo) * (Tc + 1.0f));
}

// ---------------- conversion kernels ----------------
__global__ void conv_x_kernel(const float* __restrict__ x, short* __restrict__ xb, int n) {
  int i = blockIdx.x * blockDim.x + threadIdx.x;
  int stride = gridDim.x * blockDim.x;
  for (; i < n; i += stride) xb[i] = f2bf(x[i]);
}

// pre-scales LSTM weights/bias by gate: i,f,o -> -log2e ; g -> +2log2e
__global__ void conv_layer_kernel(const float* __restrict__ Wih, const float* __restrict__ Whh,
                                  const float* __restrict__ bih, const float* __restrict__ bhh,
                                  const float* __restrict__ Wl, const float* __restrict__ Wr, int foK,
                                  short* __restrict__ wihB, short* __restrict__ whhB,
                                  short* __restrict__ wlB, short* __restrict__ wrB,
                                  float* __restrict__ bsum) {
  int i = blockIdx.x * blockDim.x + threadIdx.x;
  if (i < 512 * HID) {
    float sc = ((i >> 14) == 2) ? PK2 : NK1;  // gate = row>>7 = i>>14
    wihB[i] = f2bf(Wih[i] * sc);
    whhB[i] = f2bf(Whh[i] * sc);
  }
  if (i < foK) { wlB[i] = f2bf(Wl[i]); wrB[i] = f2bf(Wr[i]); }
  if (i < 512) bsum[i] = (bih[i] + bhh[i]) * (((i >> 7) == 2) ? PK2 : NK1);
}

// ---------------- persistent P-GEMM: P = A @ Wih^T + bias -> bf16 [M,512] ----
// Operand-swapped MFMA (A=weights) -> lane owns 4 consecutive out-cols -> packed
// b64 epilogue writes. LDS-bounce -> coalesced b128 global stores.
#define OSTR 524
__global__ __launch_bounds__(256, 2) void pgemm_kernel(
    const short* __restrict__ A, const short* __restrict__ W,
    const float* __restrict__ bias, short* __restrict__ out, int M, int ntiles) {
  __shared__ short ldsO[32 * OSTR];
  const int tid = threadIdx.x;
  const int wave = tid >> 6, lane = tid & 63;
  const int quad = lane >> 4, nn = lane & 15;

  short8 wreg[4][8];
#pragma unroll
  for (int kt = 0; kt < 4; ++kt)
#pragma unroll
    for (int nt = 0; nt < 8; ++nt)
      wreg[kt][nt] = *(const short8*)(W + (size_t)(wave * 128 + nt * 16 + nn) * HID + kt * 32 + quad * 8);
  f32x4 bias4[8];
#pragma unroll
  for (int nt = 0; nt < 8; ++nt)
#pragma unroll
    for (int r = 0; r < 4; ++r) bias4[nt][r] = bias[wave * 128 + nt * 16 + quad * 4 + r];

  const f32x4 zero4 = {0.f, 0.f, 0.f, 0.f};
#pragma unroll 1
  for (int rt = blockIdx.x; rt < ntiles; rt += gridDim.x) {
    const int row0 = rt * 32;
    f32x4 acc[2][8];
#pragma unroll
    for (int b = 0; b < 2; ++b)
#pragma unroll
      for (int nt = 0; nt < 8; ++nt) acc[b][nt] = zero4;
#pragma unroll
    for (int kt = 0; kt < 4; ++kt) {
      int r0 = row0 + nn;      if (r0 > M - 1) r0 = M - 1;
      int r1 = row0 + 16 + nn; if (r1 > M - 1) r1 = M - 1;
      short8 af0 = *(const short8*)(A + (size_t)r0 * HID + kt * 32 + quad * 8);
      short8 af1 = *(const short8*)(A + (size_t)r1 * HID + kt * 32 + quad * 8);
#pragma unroll
      for (int nt = 0; nt < 8; ++nt) {
        acc[0][nt] = __builtin_amdgcn_mfma_f32_16x16x32_bf16(wreg[kt][nt], af0, acc[0][nt], 0, 0, 0);
        acc[1][nt] = __builtin_amdgcn_mfma_f32_16x16x32_bf16(wreg[kt][nt], af1, acc[1][nt], 0, 0, 0);
      }
    }
    BAR_LGKM();  // previous iteration's ldsO reads complete
#pragma unroll
    for (int b = 0; b < 2; ++b)
#pragma unroll
      for (int nt = 0; nt < 8; ++nt) {
        f32x4 v = acc[b][nt] + bias4[nt];
        uint2 pk;
        pk.x = pack_bf2(v[0], v[1]);
        pk.y = pack_bf2(v[2], v[3]);
        *(uint2*)(ldsO + (b * 16 + nn) * OSTR + wave * 128 + nt * 16 + quad * 4) = pk;
      }
    BAR_LGKM();
#pragma unroll
    for (int idx = tid; idx < 32 * 64; idx += 256) {
      int row = idx >> 6, c8 = (idx & 63) * 8;
      if (row0 + row < M)
        *(short8*)(out + (size_t)(row0 + row) * 512 + c8) = *(const short8*)(ldsO + row * OSTR + c8);
    }
  }
}

// ---------------- fused output GEMM: out = A1@Wl^T + bias + A2@Wr^T ----------
template <int FO, bool RELU, bool OUTF32>
__global__ __launch_bounds__(256, 4) void outgemm_kernel(
    const short* __restrict__ A1, const short* __restrict__ W1,
    const short* __restrict__ A2, const short* __restrict__ W2,
    const float* __restrict__ bias,
    short* __restrict__ outB, float* __restrict__ outF, int M) {
  const int NTW = FO / 64;
  __shared__ char osm[8704];
  short* ldsO = (short*)osm;  // [32][136] bf16 path
  float* ldsF = (float*)osm;  // [32][68]  f32 path
  const int tid = threadIdx.x;
  const int wave = tid >> 6, lane = tid & 63;
  const int quad = lane >> 4, nn = lane & 15;
  const int cbase = wave * (FO / 4);
  const int row0 = blockIdx.x * 32;

  short8 w1r[4][NTW], w2r[4][NTW];
#pragma unroll
  for (int kt = 0; kt < 4; ++kt)
#pragma unroll
    for (int nt = 0; nt < NTW; ++nt) {
      w1r[kt][nt] = *(const short8*)(W1 + (size_t)(cbase + nt * 16 + nn) * HID + kt * 32 + quad * 8);
      w2r[kt][nt] = *(const short8*)(W2 + (size_t)(cbase + nt * 16 + nn) * HID + kt * 32 + quad * 8);
    }
  f32x4 bias4[NTW];
#pragma unroll
  for (int nt = 0; nt < NTW; ++nt)
#pragma unroll
    for (int r = 0; r < 4; ++r) bias4[nt][r] = bias[cbase + nt * 16 + quad * 4 + r];

  const f32x4 zero4 = {0.f, 0.f, 0.f, 0.f};
  f32x4 acc[2][NTW];
#pragma unroll
  for (int b = 0; b < 2; ++b)
#pragma unroll
    for (int nt = 0; nt < NTW; ++nt) acc[b][nt] = zero4;

#pragma unroll
  for (int kt = 0; kt < 4; ++kt) {
    int r0 = row0 + nn;      if (r0 > M - 1) r0 = M - 1;
    int r1 = row0 + 16 + nn; if (r1 > M - 1) r1 = M - 1;
    short8 a10 = *(const short8*)(A1 + (size_t)r0 * HID + kt * 32 + quad * 8);
    short8 a11 = *(const short8*)(A1 + (size_t)r1 * HID + kt * 32 + quad * 8);
    short8 a20 = *(const short8*)(A2 + (size_t)r0 * HID + kt * 32 + quad * 8);
    short8 a21 = *(const short8*)(A2 + (size_t)r1 * HID + kt * 32 + quad * 8);
#pragma unroll
    for (int nt = 0; nt < NTW; ++nt) {
      acc[0][nt] = __builtin_amdgcn_mfma_f32_16x16x32_bf16(w1r[kt][nt], a10, acc[0][nt], 0, 0, 0);
      acc[1][nt] = __builtin_amdgcn_mfma_f32_16x16x32_bf16(w1r[kt][nt], a11, acc[1][nt], 0, 0, 0);
      acc[0][nt] = __builtin_amdgcn_mfma_f32_16x16x32_bf16(w2r[kt][nt], a20, acc[0][nt], 0, 0, 0);
      acc[1][nt] = __builtin_amdgcn_mfma_f32_16x16x32_bf16(w2r[kt][nt], a21, acc[1][nt], 0, 0, 0);
    }
  }
#pragma unroll
  for (int b = 0; b < 2; ++b)
#pragma unroll
    for (int nt = 0; nt < NTW; ++nt) {
      f32x4 v = acc[b][nt] + bias4[nt];
      if (RELU) {
#pragma unroll
        for (int r = 0; r < 4; ++r) v[r] = fmaxf(v[r], 0.0f);
      }
      int lrow = b * 16 + nn;
      if (OUTF32) {
        *(f32x4*)(ldsF + lrow * 68 + cbase + nt * 16 + quad * 4) = v;
      } else {
        uint2 pk;
        pk.x = pack_bf2(v[0], v[1]);
        pk.y = pack_bf2(v[2], v[3]);
        *(uint2*)(ldsO + lrow * 136 + cbase + nt * 16 + quad * 4) = pk;
      }
    }
  BAR_LGKM();
  if (OUTF32) {
#pragma unroll
    for (int idx = tid; idx < 32 * 16; idx += 256) {
      int row = idx >> 4, c4 = (idx & 15) * 4;
      if (row0 + row < M)
        *(f32x4*)(outF + (size_t)(row0 + row) * 64 + c4) = *(const f32x4*)(ldsF + row * 68 + c4);
    }
  } else {
#pragma unroll
    for (int idx = tid; idx < 32 * 16; idx += 256) {
      int row = idx >> 4, c8 = (idx & 15) * 8;
      if (row0 + row < M)
        *(short8*)(outB + (size_t)(row0 + row) * 128 + c8) = *(const short8*)(ldsO + row * 136 + c8);
    }
  }
}

// ---------------- persistent LSTM recurrence: 8 waves, gate-half split --------
// Wave w: gate = w>>1, n-half = w&1 -> wreg = 64 VGPRs -> fits 128-VGPR budget
// -> 4 waves/SIMD (2 blocks/CU). MFMA computes G^T = Whh_chunk @ h^T so each
// lane holds 4 consecutive G-cols -> cheap packed exchange. Cell math folded
// (5 exp2 + 2 rcp), weights pre-scaled. Gathers wave-self-consumed (rows
// [4w,4w+4)) -> LDS-only barriers, gather(t+1) issued mid-cell.
#define NPB 32
#define PSTR 520
#define GSTR 518
#define HSTR 136
#define LSTM_LDS_BYTES ((NPB * PSTR + NPB * GSTR + NPB * HSTR) * 2 + NPB * 16 * 4)  // 77184

__global__ __launch_bounds__(512, 4) void lstm_steps_kernel(
    const short* __restrict__ P, const short* __restrict__ Whh,
    const int* __restrict__ src, short* __restrict__ aggr, int M) {
  extern __shared__ char smem[];
  short* ldsP = (short*)smem;             // [32][520]
  short* ldsG = ldsP + NPB * PSTR;        // [32][518] (512 used)
  short* ldsH = ldsG + NPB * GSTR;        // [32][136]
  int* srcL = (int*)(ldsH + NPB * HSTR);  // [512]

  const int tid = threadIdx.x;
  const int wave = tid >> 6, lane = tid & 63;
  const int quad = lane >> 4, nn = lane & 15;
  const int gate = wave >> 1, half = wave & 1;
  const int nodeBase = blockIdx.x * NPB;

  // Whh fragments: this wave's G-cols [gate*128 + half*64, +64)
  short8 wreg[4][4];
#pragma unroll
  for (int kt = 0; kt < 4; ++kt)
#pragma unroll
    for (int nt = 0; nt < 4; ++nt)
      wreg[kt][nt] = *(const short8*)(Whh + (size_t)(gate * 128 + half * 64 + nt * 16 + nn) * HID + kt * 32 + quad * 8);

  {
    int node = nodeBase + (tid >> 4);
    srcL[tid] = (node < M) ? src[nodeBase * 16 + tid] : 0;
  }
  for (int i = tid; i < NPB * HSTR; i += 512) ldsH[i] = 0;

  float c_st[8];
#pragma unroll
  for (int j = 0; j < 8; ++j) c_st[j] = 0.f;

  const int crow = tid >> 4;  // 0..31; wave w owns rows [4w, 4w+4)
  const int cc = tid & 15;    // col-group: cols [cc*8, cc*8+8)

  __syncthreads();

  // prologue gather t=0
#pragma unroll
  for (int i = 0; i < 4; ++i) {
    int rrow = wave * 4 + i;
    int srow = srcL[rrow * 16 + 0];
    __builtin_amdgcn_global_load_lds(
        (const __attribute__((address_space(1))) unsigned int*)(P + (size_t)srow * 512 + lane * 8),
        (__attribute__((address_space(3))) unsigned int*)(ldsP + rrow * PSTR), 16, 0, 0);
  }

  const f32x4 zero4 = {0.f, 0.f, 0.f, 0.f};

#pragma unroll 1
  for (int t = 0; t < 16; ++t) {
    // ---- G^T = Whh_chunk @ h(t-1)^T ----
    f32x4 acc[2][4];
#pragma unroll
    for (int nb = 0; nb < 2; ++nb)
#pragma unroll
      for (int nt = 0; nt < 4; ++nt) acc[nb][nt] = zero4;
#pragma unroll
    for (int kt = 0; kt < 4; ++kt) {
      short8 hb0 = *(const short8*)(ldsH + (0 * 16 + nn) * HSTR + kt * 32 + quad * 8);
      short8 hb1 = *(const short8*)(ldsH + (1 * 16 + nn) * HSTR + kt * 32 + quad * 8);
#pragma unroll
      for (int nt = 0; nt < 4; ++nt) {
        acc[0][nt] = __builtin_amdgcn_mfma_f32_16x16x32_bf16(wreg[kt][nt], hb0, acc[0][nt], 0, 0, 0);
        acc[1][nt] = __builtin_amdgcn_mfma_f32_16x16x32_bf16(wreg[kt][nt], hb1, acc[1][nt], 0, 0, 0);
      }
    }
    // ---- exchange: D col = node(nn), row = 4 consecutive G-cols -> packed b32 ----
#pragma unroll
    for (int nb = 0; nb < 2; ++nb)
#pragma unroll
      for (int nt = 0; nt < 4; ++nt) {
        int c0 = gate * 128 + half * 64 + nt * 16 + quad * 4;
        int* dst = (int*)(ldsG + (nb * 16 + nn) * GSTR + c0);
        dst[0] = pack_bf2(acc[nb][nt][0], acc[nb][nt][1]);
        dst[1] = pack_bf2(acc[nb][nt][2], acc[nb][nt][3]);
      }

    BAR_LGKM();  // ldsG visible; all ldsH reads complete (no vmcnt drain)
    WAIT_VM0();  // this wave's gather(t) landed in its own ldsP rows

    // ---- stage this wave's P (rows about to be re-gathered) ----
    const short* pR = ldsP + crow * PSTR;
    int4v Ps[4];
#pragma unroll
    for (int g = 0; g < 4; ++g) Ps[g] = *(const int4v*)(pR + g * 128 + cc * 8);
    WAIT_LGKM();  // staging reads complete -> safe to overwrite own rows
    if (t < 15) {
#pragma unroll
      for (int i = 0; i < 4; ++i) {
        int rrow = wave * 4 + i;
        int srow = srcL[rrow * 16 + t + 1];
        __builtin_amdgcn_global_load_lds(
            (const __attribute__((address_space(1))) unsigned int*)(P + (size_t)srow * 512 + lane * 8),
            (__attribute__((address_space(3))) unsigned int*)(ldsP + rrow * PSTR), 16, 0, 0);
      }
    }

    // ---- cell: thread owns (crow, cols cc*8..+8) ----
    const int* gB = (const int*)(ldsG + crow * GSTR) + cc * 4;
    int4v hv;
#pragma unroll
    for (int p = 0; p < 4; ++p) {
      int wi = gB[p];
      int wf = gB[64 + p];
      int wg = gB[128 + p];
      int wo = gB[192 + p];
      float si0, si1, sf0, sf1, sg0, sg1, so0, so1;
      unpack2(wi, si0, si1);
      unpack2(wf, sf0, sf1);
      unpack2(wg, sg0, sg1);
      unpack2(wo, so0, so1);
      float pi0, pi1, pf0, pf1, pg0, pg1, po0, po1;
      unpack2(((const int*)&Ps[0])[p], pi0, pi1);
      unpack2(((const int*)&Ps[1])[p], pf0, pf1);
      unpack2(((const int*)&Ps[2])[p], pg0, pg1);
      unpack2(((const int*)&Ps[3])[p], po0, po1);
      float h0 = lstm_elem(si0 + pi0, sf0 + pf0, sg0 + pg0, so0 + po0, c_st[2 * p]);
      float h1 = lstm_elem(si1 + pi1, sf1 + pf1, sg1 + pg1, so1 + po1, c_st[2 * p + 1]);
      ((int*)&hv)[p] = pack_bf2(h0, h1);
    }
    *(int4v*)(ldsH + crow * HSTR + cc * 8) = hv;
    BAR_LGKM();  // h(t) visible; ldsG reads complete
  }

  // ---- final h -> aggr (512 threads = exactly 32 rows x 16 chunks) ----
  {
    int rrow = tid >> 4, off = (tid & 15) * 8;
    int node = nodeBase + rrow;
    if (node < M)
      *(short8*)(aggr + (size_t)node * HID + off) = *(const short8*)(ldsH + rrow * HSTR + off);
  }
}

// ---------------- launcher ----------------
extern "C" void kernel_launch(void* const* d_in, const int* in_sizes, int n_in,
                              void* d_out, int out_size, void* d_ws, size_t ws_size,
                              hipStream_t stream) {
  const float* x = (const float*)d_in[0];
  const int* src = (const int*)d_in[1];
  const float* Wih[3] = {(const float*)d_in[2], (const float*)d_in[9], (const float*)d_in[16]};
  const float* Whh[3] = {(const float*)d_in[3], (const float*)d_in[10], (const float*)d_in[17]};
  const float* bih[3] = {(const float*)d_in[4], (const float*)d_in[11], (const float*)d_in[18]};
  const float* bhh[3] = {(const float*)d_in[5], (const float*)d_in[12], (const float*)d_in[19]};
  const float* Wl[3]  = {(const float*)d_in[6], (const float*)d_in[13], (const float*)d_in[20]};
  const float* bl[3]  = {(const float*)d_in[7], (const float*)d_in[14], (const float*)d_in[21]};
  const float* Wr[3]  = {(const float*)d_in[8], (const float*)d_in[15], (const float*)d_in[22]};

  const int M = in_sizes[0] / HID;  // 50000

  char* ws = (char*)d_ws;
  size_t off = 0;
  auto alloc = [&](size_t bytes) -> void* {
    void* p = ws + off;
    off += (bytes + 255) & ~(size_t)255;
    return p;
  };
  short* curA = (short*)alloc((size_t)M * HID * 2);
  short* curB = (short*)alloc((size_t)M * HID * 2);
  short* aggr = (short*)alloc((size_t)M * HID * 2);
  short* Pbuf = (short*)alloc((size_t)M * 512 * 2);
  short* wihB = (short*)alloc(512 * HID * 2);
  short* whhB = (short*)alloc(512 * HID * 2);
  short* wlB  = (short*)alloc(HID * HID * 2);
  short* wrB  = (short*)alloc(HID * HID * 2);
  float* bsum = (float*)alloc(512 * 4);

  const int nblk = (M + NPB - 1) / NPB;  // 1563
  const int ntiles = (M + 31) / 32;      // 1563

  (void)hipFuncSetAttribute((const void*)lstm_steps_kernel,
                            hipFuncAttributeMaxDynamicSharedMemorySize, LSTM_LDS_BYTES);

  conv_x_kernel<<<2048, 256, 0, stream>>>(x, curA, M * HID);

  short* cur = curA;
  short* nxt = curB;
  for (int l = 0; l < 3; ++l) {
    const int Fo = (l == 2) ? 64 : 128;
    conv_layer_kernel<<<256, 256, 0, stream>>>(Wih[l], Whh[l], bih[l], bhh[l], Wl[l], Wr[l],
                                               Fo * HID, wihB, whhB, wlB, wrB, bsum);
    pgemm_kernel<<<512, 256, 0, stream>>>(cur, wihB, bsum, Pbuf, M, ntiles);
    lstm_steps_kernel<<<nblk, 512, LSTM_LDS_BYTES, stream>>>(Pbuf, whhB, src, aggr, M);
    if (l < 2) {
      outgemm_kernel<128, true, false><<<ntiles, 256, 0, stream>>>(
          aggr, wlB, cur, wrB, bl[l], nxt, nullptr, M);
      short* tswap = cur; cur = nxt; nxt = tswap;
    } else {
      outgemm_kernel<64, false, true><<<ntiles, 256, 0, stream>>>(
          aggr, wlB, cur, wrB, bl[l], nullptr, (float*)d_out, M);
    }
  }
}

// Round 5
// 939.451 us; speedup vs baseline: 7.4458x; 1.1538x over previous
//
#include <hip/hip_runtime.h>
#include <cstddef>
#include <cstdint>

typedef __attribute__((ext_vector_type(4))) float f32x4;
typedef __attribute__((ext_vector_type(8))) short short8;

#define HID 128
#define NK1 -1.4426950408889634f  // -log2(e)
#define PK2 2.8853900817779268f   // +2*log2(e)

// LDS-only barrier: no vmcnt(0) drain (gathers stay in flight across it).
#define BAR_LGKM() __asm__ volatile("s_waitcnt lgkmcnt(0)\ns_barrier" ::: "memory")
#define WAIT_VM0() __asm__ volatile("s_waitcnt vmcnt(0)" ::: "memory")

__device__ __forceinline__ short f2bf(float f) {
  unsigned u = __builtin_bit_cast(unsigned, f);
  u += 0x7FFFu + ((u >> 16) & 1u);
  return (short)(u >> 16);
}
// pack two f32 -> two bf16 (round-half-up) in one u32 via v_perm
__device__ __forceinline__ unsigned pack_bf2(float a, float b) {
  unsigned ua = __builtin_bit_cast(unsigned, a) + 0x8000u;
  unsigned ub = __builtin_bit_cast(unsigned, b) + 0x8000u;
  return __builtin_amdgcn_perm(ub, ua, 0x07060302u);
}
__device__ __forceinline__ void unpack2(int w, float& lo, float& hi) {
  lo = __builtin_bit_cast(float, (unsigned)(w << 16));
  hi = __builtin_bit_cast(float, (unsigned)w & 0xffff0000u);
}

// folded LSTM cell: inputs are PRE-SCALED pre-activations
// si,sf,so = -log2e*(gate), sg = 2log2e*(g). 5 exp2 + 2 rcp.
__device__ __forceinline__ float lstm_elem(float si, float sf, float sg, float so, float& c) {
  float Ei = __builtin_amdgcn_exp2f(si);
  float Ef = __builtin_amdgcn_exp2f(sf);
  float Tg = __builtin_amdgcn_exp2f(sg);
  float Eo = __builtin_amdgcn_exp2f(so);
  float u = 1.0f + Ei, w = 1.0f + Ef, v = Tg + 1.0f, Tm = Tg - 1.0f;
  float t0 = u * v;
  float num = __builtin_fmaf(c, t0, w * Tm);
  float cn = num * __builtin_amdgcn_rcpf(w * t0);
  c = cn;
  float Tc = __builtin_amdgcn_exp2f(PK2 * cn);
  return (Tc - 1.0f) * __builtin_amdgcn_rcpf((1.0f + Eo) * (Tc + 1.0f));
}

// ---------------- conversion kernels ----------------
__global__ void conv_x_kernel(const float* __restrict__ x, short* __restrict__ xb, int n) {
  int i = blockIdx.x * blockDim.x + threadIdx.x;
  int stride = gridDim.x * blockDim.x;
  for (; i < n; i += stride) xb[i] = f2bf(x[i]);
}

// pre-scales LSTM weights/bias by gate: i,f,o -> -log2e ; g -> +2log2e
__global__ void conv_layer_kernel(const float* __restrict__ Wih, const float* __restrict__ Whh,
                                  const float* __restrict__ bih, const float* __restrict__ bhh,
                                  const float* __restrict__ Wl, const float* __restrict__ Wr, int foK,
                                  short* __restrict__ wihB, short* __restrict__ whhB,
                                  short* __restrict__ wlB, short* __restrict__ wrB,
                                  float* __restrict__ bsum) {
  int i = blockIdx.x * blockDim.x + threadIdx.x;
  if (i < 512 * HID) {
    float sc = ((i >> 14) == 2) ? PK2 : NK1;  // gate = row>>7 = i>>14
    wihB[i] = f2bf(Wih[i] * sc);
    whhB[i] = f2bf(Whh[i] * sc);
  }
  if (i < foK) { wlB[i] = f2bf(Wl[i]); wrB[i] = f2bf(Wr[i]); }
  if (i < 512) bsum[i] = (bih[i] + bhh[i]) * (((i >> 7) == 2) ? PK2 : NK1);
}

// ---------------- persistent P-GEMM: P = A @ Wih^T + bias -> bf16 [M,512] ----
#define OSTR 524
__global__ __launch_bounds__(256, 2) void pgemm_kernel(
    const short* __restrict__ A, const short* __restrict__ W,
    const float* __restrict__ bias, short* __restrict__ out, int M, int ntiles) {
  __shared__ short ldsO[32 * OSTR];
  const int tid = threadIdx.x;
  const int wave = tid >> 6, lane = tid & 63;
  const int quad = lane >> 4, nn = lane & 15;

  short8 wreg[4][8];
#pragma unroll
  for (int kt = 0; kt < 4; ++kt)
#pragma unroll
    for (int nt = 0; nt < 8; ++nt)
      wreg[kt][nt] = *(const short8*)(W + (size_t)(wave * 128 + nt * 16 + nn) * HID + kt * 32 + quad * 8);
  f32x4 bias4[8];
#pragma unroll
  for (int nt = 0; nt < 8; ++nt)
#pragma unroll
    for (int r = 0; r < 4; ++r) bias4[nt][r] = bias[wave * 128 + nt * 16 + quad * 4 + r];

  const f32x4 zero4 = {0.f, 0.f, 0.f, 0.f};
#pragma unroll 1
  for (int rt = blockIdx.x; rt < ntiles; rt += gridDim.x) {
    const int row0 = rt * 32;
    f32x4 acc[2][8];
#pragma unroll
    for (int b = 0; b < 2; ++b)
#pragma unroll
      for (int nt = 0; nt < 8; ++nt) acc[b][nt] = zero4;
#pragma unroll
    for (int kt = 0; kt < 4; ++kt) {
      int r0 = row0 + nn;      if (r0 > M - 1) r0 = M - 1;
      int r1 = row0 + 16 + nn; if (r1 > M - 1) r1 = M - 1;
      short8 af0 = *(const short8*)(A + (size_t)r0 * HID + kt * 32 + quad * 8);
      short8 af1 = *(const short8*)(A + (size_t)r1 * HID + kt * 32 + quad * 8);
#pragma unroll
      for (int nt = 0; nt < 8; ++nt) {
        acc[0][nt] = __builtin_amdgcn_mfma_f32_16x16x32_bf16(wreg[kt][nt], af0, acc[0][nt], 0, 0, 0);
        acc[1][nt] = __builtin_amdgcn_mfma_f32_16x16x32_bf16(wreg[kt][nt], af1, acc[1][nt], 0, 0, 0);
      }
    }
    BAR_LGKM();  // previous iteration's ldsO reads complete
#pragma unroll
    for (int b = 0; b < 2; ++b)
#pragma unroll
      for (int nt = 0; nt < 8; ++nt) {
        f32x4 v = acc[b][nt] + bias4[nt];
        uint2 pk;
        pk.x = pack_bf2(v[0], v[1]);
        pk.y = pack_bf2(v[2], v[3]);
        *(uint2*)(ldsO + (b * 16 + nn) * OSTR + wave * 128 + nt * 16 + quad * 4) = pk;
      }
    BAR_LGKM();
#pragma unroll
    for (int idx = tid; idx < 32 * 64; idx += 256) {
      int row = idx >> 6, c8 = (idx & 63) * 8;
      if (row0 + row < M)
        *(short8*)(out + (size_t)(row0 + row) * 512 + c8) = *(const short8*)(ldsO + row * OSTR + c8);
    }
  }
}

// ---------------- fused output GEMM: out = A1@Wl^T + bias + A2@Wr^T ----------
template <int FO, bool RELU, bool OUTF32>
__global__ __launch_bounds__(256, 4) void outgemm_kernel(
    const short* __restrict__ A1, const short* __restrict__ W1,
    const short* __restrict__ A2, const short* __restrict__ W2,
    const float* __restrict__ bias,
    short* __restrict__ outB, float* __restrict__ outF, int M) {
  const int NTW = FO / 64;
  __shared__ char osm[8704];
  short* ldsO = (short*)osm;  // [32][136] bf16 path
  float* ldsF = (float*)osm;  // [32][68]  f32 path
  const int tid = threadIdx.x;
  const int wave = tid >> 6, lane = tid & 63;
  const int quad = lane >> 4, nn = lane & 15;
  const int cbase = wave * (FO / 4);
  const int row0 = blockIdx.x * 32;

  short8 w1r[4][NTW], w2r[4][NTW];
#pragma unroll
  for (int kt = 0; kt < 4; ++kt)
#pragma unroll
    for (int nt = 0; nt < NTW; ++nt) {
      w1r[kt][nt] = *(const short8*)(W1 + (size_t)(cbase + nt * 16 + nn) * HID + kt * 32 + quad * 8);
      w2r[kt][nt] = *(const short8*)(W2 + (size_t)(cbase + nt * 16 + nn) * HID + kt * 32 + quad * 8);
    }
  f32x4 bias4[NTW];
#pragma unroll
  for (int nt = 0; nt < NTW; ++nt)
#pragma unroll
    for (int r = 0; r < 4; ++r) bias4[nt][r] = bias[cbase + nt * 16 + quad * 4 + r];

  const f32x4 zero4 = {0.f, 0.f, 0.f, 0.f};
  f32x4 acc[2][NTW];
#pragma unroll
  for (int b = 0; b < 2; ++b)
#pragma unroll
    for (int nt = 0; nt < NTW; ++nt) acc[b][nt] = zero4;

#pragma unroll
  for (int kt = 0; kt < 4; ++kt) {
    int r0 = row0 + nn;      if (r0 > M - 1) r0 = M - 1;
    int r1 = row0 + 16 + nn; if (r1 > M - 1) r1 = M - 1;
    short8 a10 = *(const short8*)(A1 + (size_t)r0 * HID + kt * 32 + quad * 8);
    short8 a11 = *(const short8*)(A1 + (size_t)r1 * HID + kt * 32 + quad * 8);
    short8 a20 = *(const short8*)(A2 + (size_t)r0 * HID + kt * 32 + quad * 8);
    short8 a21 = *(const short8*)(A2 + (size_t)r1 * HID + kt * 32 + quad * 8);
#pragma unroll
    for (int nt = 0; nt < NTW; ++nt) {
      acc[0][nt] = __builtin_amdgcn_mfma_f32_16x16x32_bf16(w1r[kt][nt], a10, acc[0][nt], 0, 0, 0);
      acc[1][nt] = __builtin_amdgcn_mfma_f32_16x16x32_bf16(w1r[kt][nt], a11, acc[1][nt], 0, 0, 0);
      acc[0][nt] = __builtin_amdgcn_mfma_f32_16x16x32_bf16(w2r[kt][nt], a20, acc[0][nt], 0, 0, 0);
      acc[1][nt] = __builtin_amdgcn_mfma_f32_16x16x32_bf16(w2r[kt][nt], a21, acc[1][nt], 0, 0, 0);
    }
  }
#pragma unroll
  for (int b = 0; b < 2; ++b)
#pragma unroll
    for (int nt = 0; nt < NTW; ++nt) {
      f32x4 v = acc[b][nt] + bias4[nt];
      if (RELU) {
#pragma unroll
        for (int r = 0; r < 4; ++r) v[r] = fmaxf(v[r], 0.0f);
      }
      int lrow = b * 16 + nn;
      if (OUTF32) {
        *(f32x4*)(ldsF + lrow * 68 + cbase + nt * 16 + quad * 4) = v;
      } else {
        uint2 pk;
        pk.x = pack_bf2(v[0], v[1]);
        pk.y = pack_bf2(v[2], v[3]);
        *(uint2*)(ldsO + lrow * 136 + cbase + nt * 16 + quad * 4) = pk;
      }
    }
  BAR_LGKM();
  if (OUTF32) {
#pragma unroll
    for (int idx = tid; idx < 32 * 16; idx += 256) {
      int row = idx >> 4, c4 = (idx & 15) * 4;
      if (row0 + row < M)
        *(f32x4*)(outF + (size_t)(row0 + row) * 64 + c4) = *(const f32x4*)(ldsF + row * 68 + c4);
    }
  } else {
#pragma unroll
    for (int idx = tid; idx < 32 * 16; idx += 256) {
      int row = idx >> 4, c8 = (idx & 15) * 8;
      if (row0 + row < M)
        *(short8*)(outB + (size_t)(row0 + row) * 128 + c8) = *(const short8*)(ldsO + row * 136 + c8);
    }
  }
}

// ---------------- persistent LSTM recurrence: NO gate exchange ----------------
// 512 thr = 8 waves, 32 nodes. Wave w holds, for ALL 4 gates, Whh rows
// [q*128 + w*16, +16) (64 VGPRs). MFMA D-layout then gives each lane i,f,g,o
// for the same (node, col) IN REGISTERS (acc[nb][q][r], col = w*16+quad*4+r,
// node = nn+16nb) -> the cell runs on f32 register G with no LDS round-trip.
// Per step: MFMA -> vmcnt(0)+LDS-barrier -> cell (reads ldsP b64, writes h
// packed b64) -> LDS-barrier -> issue gather(t+1) (covered by next MFMA+cell).
#define NPB 32
#define PSTR 520  // 16B-aligned rows; 260 words % 32 = 4 -> 2-way (free) banking
#define HSTR 136
#define LSTM_LDS_BYTES ((NPB * PSTR + NPB * HSTR) * 2 + NPB * 16 * 4)  // 44032

__global__ __launch_bounds__(512, 4) void lstm_steps_kernel(
    const short* __restrict__ P, const short* __restrict__ Whh,
    const int* __restrict__ src, short* __restrict__ aggr, int M) {
  extern __shared__ char smem[];
  short* ldsP = (short*)smem;             // [32][520]
  short* ldsH = ldsP + NPB * PSTR;        // [32][136]
  int* srcL = (int*)(ldsH + NPB * HSTR);  // [512]

  const int tid = threadIdx.x;
  const int wave = tid >> 6, lane = tid & 63;
  const int quad = lane >> 4, nn = lane & 15;
  const int nodeBase = blockIdx.x * NPB;

  // Whh fragments: for each gate q, rows [q*128 + wave*16, +16)
  short8 wreg[4][4];  // [kt][q]
#pragma unroll
  for (int kt = 0; kt < 4; ++kt)
#pragma unroll
    for (int q = 0; q < 4; ++q)
      wreg[kt][q] = *(const short8*)(Whh + (size_t)(q * 128 + wave * 16 + nn) * HID + kt * 32 + quad * 8);

  {
    int node = nodeBase + (tid >> 4);
    srcL[tid] = (node < M) ? src[nodeBase * 16 + tid] : 0;
  }

  float c_st[8];  // [nb*4 + r]
#pragma unroll
  for (int j = 0; j < 8; ++j) c_st[j] = 0.f;

  __syncthreads();  // srcL visible (full drain OK once)

  // prologue: gather t=0 (wave's own 4 rows, 1KB each, lane*16B coalesced)
#pragma unroll
  for (int i = 0; i < 4; ++i) {
    int rrow = wave * 4 + i;
    int srow = srcL[rrow * 16 + 0];
    __builtin_amdgcn_global_load_lds(
        (const __attribute__((address_space(1))) unsigned int*)(P + (size_t)srow * 512 + lane * 8),
        (__attribute__((address_space(3))) unsigned int*)(ldsP + rrow * PSTR), 16, 0, 0);
  }

  const f32x4 zero4 = {0.f, 0.f, 0.f, 0.f};

#pragma unroll 1
  for (int t = 0; t < 16; ++t) {
    // ---- G = Whh_rows @ h(t-1)^T : all 4 gates' col-chunk for this wave ----
    f32x4 acc[2][4];  // [nb][gate]
#pragma unroll
    for (int nb = 0; nb < 2; ++nb)
#pragma unroll
      for (int q = 0; q < 4; ++q) acc[nb][q] = zero4;
    if (t) {
#pragma unroll
      for (int kt = 0; kt < 4; ++kt) {
        short8 hb0 = *(const short8*)(ldsH + (0 * 16 + nn) * HSTR + kt * 32 + quad * 8);
        short8 hb1 = *(const short8*)(ldsH + (1 * 16 + nn) * HSTR + kt * 32 + quad * 8);
#pragma unroll
        for (int q = 0; q < 4; ++q) {
          acc[0][q] = __builtin_amdgcn_mfma_f32_16x16x32_bf16(wreg[kt][q], hb0, acc[0][q], 0, 0, 0);
          acc[1][q] = __builtin_amdgcn_mfma_f32_16x16x32_bf16(wreg[kt][q], hb1, acc[1][q], 0, 0, 0);
        }
      }
    }

    WAIT_VM0();  // drain gather(t) (covered by MFMA phase; t=0: once, cold)
    BAR_LGKM();  // all waves drained -> ldsP(t) readable; MFMA h-reads done

    // ---- cell: lane owns (node nn+16nb, cols wave*16+quad*4..+4), 4 gates ----
#pragma unroll
    for (int nb = 0; nb < 2; ++nb) {
      const short* pR = ldsP + (nb * 16 + nn) * PSTR + wave * 16 + quad * 4;
      uint2 pw0 = *(const uint2*)(pR + 0 * 128);
      uint2 pw1 = *(const uint2*)(pR + 1 * 128);
      uint2 pw2 = *(const uint2*)(pR + 2 * 128);
      uint2 pw3 = *(const uint2*)(pR + 3 * 128);
      float s0[4], s1[4], s2[4], s3[4];
      unpack2(pw0.x, s0[0], s0[1]); unpack2(pw0.y, s0[2], s0[3]);
      unpack2(pw1.x, s1[0], s1[1]); unpack2(pw1.y, s1[2], s1[3]);
      unpack2(pw2.x, s2[0], s2[1]); unpack2(pw2.y, s2[2], s2[3]);
      unpack2(pw3.x, s3[0], s3[1]); unpack2(pw3.y, s3[2], s3[3]);
      float hv[4];
#pragma unroll
      for (int r = 0; r < 4; ++r) {
        hv[r] = lstm_elem(acc[nb][0][r] + s0[r], acc[nb][1][r] + s1[r],
                          acc[nb][2][r] + s2[r], acc[nb][3][r] + s3[r], c_st[nb * 4 + r]);
      }
      uint2 pk;
      pk.x = pack_bf2(hv[0], hv[1]);
      pk.y = pack_bf2(hv[2], hv[3]);
      *(uint2*)(ldsH + (nb * 16 + nn) * HSTR + wave * 16 + quad * 4) = pk;
    }

    BAR_LGKM();  // h(t) visible; all waves' ldsP(t) reads complete

    // ---- issue gather(t+1): safe (all readers past), covered until next drain
    if (t < 15) {
#pragma unroll
      for (int i = 0; i < 4; ++i) {
        int rrow = wave * 4 + i;
        int srow = srcL[rrow * 16 + t + 1];
        __builtin_amdgcn_global_load_lds(
            (const __attribute__((address_space(1))) unsigned int*)(P + (size_t)srow * 512 + lane * 8),
            (__attribute__((address_space(3))) unsigned int*)(ldsP + rrow * PSTR), 16, 0, 0);
      }
    }
  }

  // ---- final h -> aggr (512 threads = exactly 32 rows x 16 chunks) ----
  {
    int rrow = tid >> 4, off = (tid & 15) * 8;
    int node = nodeBase + rrow;
    if (node < M)
      *(short8*)(aggr + (size_t)node * HID + off) = *(const short8*)(ldsH + rrow * HSTR + off);
  }
}

// ---------------- launcher ----------------
extern "C" void kernel_launch(void* const* d_in, const int* in_sizes, int n_in,
                              void* d_out, int out_size, void* d_ws, size_t ws_size,
                              hipStream_t stream) {
  const float* x = (const float*)d_in[0];
  const int* src = (const int*)d_in[1];
  const float* Wih[3] = {(const float*)d_in[2], (const float*)d_in[9], (const float*)d_in[16]};
  const float* Whh[3] = {(const float*)d_in[3], (const float*)d_in[10], (const float*)d_in[17]};
  const float* bih[3] = {(const float*)d_in[4], (const float*)d_in[11], (const float*)d_in[18]};
  const float* bhh[3] = {(const float*)d_in[5], (const float*)d_in[12], (const float*)d_in[19]};
  const float* Wl[3]  = {(const float*)d_in[6], (const float*)d_in[13], (const float*)d_in[20]};
  const float* bl[3]  = {(const float*)d_in[7], (const float*)d_in[14], (const float*)d_in[21]};
  const float* Wr[3]  = {(const float*)d_in[8], (const float*)d_in[15], (const float*)d_in[22]};

  const int M = in_sizes[0] / HID;  // 50000

  char* ws = (char*)d_ws;
  size_t off = 0;
  auto alloc = [&](size_t bytes) -> void* {
    void* p = ws + off;
    off += (bytes + 255) & ~(size_t)255;
    return p;
  };
  short* curA = (short*)alloc((size_t)M * HID * 2);
  short* curB = (short*)alloc((size_t)M * HID * 2);
  short* aggr = (short*)alloc((size_t)M * HID * 2);
  short* Pbuf = (short*)alloc((size_t)M * 512 * 2);
  short* wihB = (short*)alloc(512 * HID * 2);
  short* whhB = (short*)alloc(512 * HID * 2);
  short* wlB  = (short*)alloc(HID * HID * 2);
  short* wrB  = (short*)alloc(HID * HID * 2);
  float* bsum = (float*)alloc(512 * 4);

  const int nblk = (M + NPB - 1) / NPB;  // 1563
  const int ntiles = (M + 31) / 32;      // 1563

  (void)hipFuncSetAttribute((const void*)lstm_steps_kernel,
                            hipFuncAttributeMaxDynamicSharedMemorySize, LSTM_LDS_BYTES);

  conv_x_kernel<<<2048, 256, 0, stream>>>(x, curA, M * HID);

  short* cur = curA;
  short* nxt = curB;
  for (int l = 0; l < 3; ++l) {
    const int Fo = (l == 2) ? 64 : 128;
    conv_layer_kernel<<<256, 256, 0, stream>>>(Wih[l], Whh[l], bih[l], bhh[l], Wl[l], Wr[l],
                                               Fo * HID, wihB, whhB, wlB, wrB, bsum);
    pgemm_kernel<<<512, 256, 0, stream>>>(cur, wihB, bsum, Pbuf, M, ntiles);
    lstm_steps_kernel<<<nblk, 512, LSTM_LDS_BYTES, stream>>>(Pbuf, whhB, src, aggr, M);
    if (l < 2) {
      outgemm_kernel<128, true, false><<<ntiles, 256, 0, stream>>>(
          aggr, wlB, cur, wrB, bl[l], nxt, nullptr, M);
      short* tswap = cur; cur = nxt; nxt = tswap;
    } else {
      outgemm_kernel<64, false, true><<<ntiles, 256, 0, stream>>>(
          aggr, wlB, cur, wrB, bl[l], nullptr, (float*)d_out, M);
    }
  }
}

// Round 6
// 867.308 us; speedup vs baseline: 8.0652x; 1.0832x over previous
//
#include <hip/hip_runtime.h>
#include <cstddef>
#include <cstdint>

typedef __attribute__((ext_vector_type(4))) float f32x4;
typedef __attribute__((ext_vector_type(8))) short short8;

#define HID 128
#define NK1 -1.4426950408889634f  // -log2(e)
#define PK2 2.8853900817779268f   // +2*log2(e)

// LDS-only barrier: no vmcnt(0) drain (gathers stay in flight across it).
#define BAR_LGKM() __asm__ volatile("s_waitcnt lgkmcnt(0)\ns_barrier" ::: "memory")
// wait until <=2 vm ops outstanding (the 2 just-issued prefetches), then barrier
#define WAIT_VM2_BAR() __asm__ volatile("s_waitcnt vmcnt(2) lgkmcnt(0)\ns_barrier" ::: "memory")

__device__ __forceinline__ short f2bf(float f) {
  unsigned u = __builtin_bit_cast(unsigned, f);
  u += 0x7FFFu + ((u >> 16) & 1u);
  return (short)(u >> 16);
}
// pack two f32 -> two bf16 (round-half-up) in one u32 via v_perm
__device__ __forceinline__ unsigned pack_bf2(float a, float b) {
  unsigned ua = __builtin_bit_cast(unsigned, a) + 0x8000u;
  unsigned ub = __builtin_bit_cast(unsigned, b) + 0x8000u;
  return __builtin_amdgcn_perm(ub, ua, 0x07060302u);
}
__device__ __forceinline__ void unpack2(int w, float& lo, float& hi) {
  lo = __builtin_bit_cast(float, (unsigned)(w << 16));
  hi = __builtin_bit_cast(float, (unsigned)w & 0xffff0000u);
}

// folded LSTM cell: inputs are PRE-SCALED pre-activations
// si,sf,so = -log2e*(gate), sg = 2log2e*(g). 5 exp2 + 2 rcp.
__device__ __forceinline__ float lstm_elem(float si, float sf, float sg, float so, float& c) {
  float Ei = __builtin_amdgcn_exp2f(si);
  float Ef = __builtin_amdgcn_exp2f(sf);
  float Tg = __builtin_amdgcn_exp2f(sg);
  float Eo = __builtin_amdgcn_exp2f(so);
  float u = 1.0f + Ei, w = 1.0f + Ef, v = Tg + 1.0f, Tm = Tg - 1.0f;
  float t0 = u * v;
  float num = __builtin_fmaf(c, t0, w * Tm);
  float cn = num * __builtin_amdgcn_rcpf(w * t0);
  c = cn;
  float Tc = __builtin_amdgcn_exp2f(PK2 * cn);
  return (Tc - 1.0f) * __builtin_amdgcn_rcpf((1.0f + Eo) * (Tc + 1.0f));
}

// ---------------- conversion kernels ----------------
__global__ void conv_x_kernel(const float* __restrict__ x, short* __restrict__ xb, int n) {
  int i = blockIdx.x * blockDim.x + threadIdx.x;
  int stride = gridDim.x * blockDim.x;
  for (; i < n; i += stride) xb[i] = f2bf(x[i]);
}

// pre-scales LSTM weights/bias by gate: i,f,o -> -log2e ; g -> +2log2e
__global__ void conv_layer_kernel(const float* __restrict__ Wih, const float* __restrict__ Whh,
                                  const float* __restrict__ bih, const float* __restrict__ bhh,
                                  const float* __restrict__ Wl, const float* __restrict__ Wr, int foK,
                                  short* __restrict__ wihB, short* __restrict__ whhB,
                                  short* __restrict__ wlB, short* __restrict__ wrB,
                                  float* __restrict__ bsum) {
  int i = blockIdx.x * blockDim.x + threadIdx.x;
  if (i < 512 * HID) {
    float sc = ((i >> 14) == 2) ? PK2 : NK1;  // gate = row>>7 = i>>14
    wihB[i] = f2bf(Wih[i] * sc);
    whhB[i] = f2bf(Whh[i] * sc);
  }
  if (i < foK) { wlB[i] = f2bf(Wl[i]); wrB[i] = f2bf(Wr[i]); }
  if (i < 512) bsum[i] = (bih[i] + bhh[i]) * (((i >> 7) == 2) ? PK2 : NK1);
}

// ---------------- persistent P-GEMM: P = A @ Wih^T + bias -> bf16 [M,512] ----
#define OSTR 524
__global__ __launch_bounds__(256, 2) void pgemm_kernel(
    const short* __restrict__ A, const short* __restrict__ W,
    const float* __restrict__ bias, short* __restrict__ out, int M, int ntiles) {
  __shared__ short ldsO[32 * OSTR];
  const int tid = threadIdx.x;
  const int wave = tid >> 6, lane = tid & 63;
  const int quad = lane >> 4, nn = lane & 15;

  short8 wreg[4][8];
#pragma unroll
  for (int kt = 0; kt < 4; ++kt)
#pragma unroll
    for (int nt = 0; nt < 8; ++nt)
      wreg[kt][nt] = *(const short8*)(W + (size_t)(wave * 128 + nt * 16 + nn) * HID + kt * 32 + quad * 8);
  f32x4 bias4[8];
#pragma unroll
  for (int nt = 0; nt < 8; ++nt)
#pragma unroll
    for (int r = 0; r < 4; ++r) bias4[nt][r] = bias[wave * 128 + nt * 16 + quad * 4 + r];

  const f32x4 zero4 = {0.f, 0.f, 0.f, 0.f};
#pragma unroll 1
  for (int rt = blockIdx.x; rt < ntiles; rt += gridDim.x) {
    const int row0 = rt * 32;
    f32x4 acc[2][8];
#pragma unroll
    for (int b = 0; b < 2; ++b)
#pragma unroll
      for (int nt = 0; nt < 8; ++nt) acc[b][nt] = zero4;
#pragma unroll
    for (int kt = 0; kt < 4; ++kt) {
      int r0 = row0 + nn;      if (r0 > M - 1) r0 = M - 1;
      int r1 = row0 + 16 + nn; if (r1 > M - 1) r1 = M - 1;
      short8 af0 = *(const short8*)(A + (size_t)r0 * HID + kt * 32 + quad * 8);
      short8 af1 = *(const short8*)(A + (size_t)r1 * HID + kt * 32 + quad * 8);
#pragma unroll
      for (int nt = 0; nt < 8; ++nt) {
        acc[0][nt] = __builtin_amdgcn_mfma_f32_16x16x32_bf16(wreg[kt][nt], af0, acc[0][nt], 0, 0, 0);
        acc[1][nt] = __builtin_amdgcn_mfma_f32_16x16x32_bf16(wreg[kt][nt], af1, acc[1][nt], 0, 0, 0);
      }
    }
    BAR_LGKM();  // previous iteration's ldsO reads complete
#pragma unroll
    for (int b = 0; b < 2; ++b)
#pragma unroll
      for (int nt = 0; nt < 8; ++nt) {
        f32x4 v = acc[b][nt] + bias4[nt];
        uint2 pk;
        pk.x = pack_bf2(v[0], v[1]);
        pk.y = pack_bf2(v[2], v[3]);
        *(uint2*)(ldsO + (b * 16 + nn) * OSTR + wave * 128 + nt * 16 + quad * 4) = pk;
      }
    BAR_LGKM();
#pragma unroll
    for (int idx = tid; idx < 32 * 64; idx += 256) {
      int row = idx >> 6, c8 = (idx & 63) * 8;
      if (row0 + row < M)
        *(short8*)(out + (size_t)(row0 + row) * 512 + c8) = *(const short8*)(ldsO + row * OSTR + c8);
    }
  }
}

// ---------------- fused output GEMM: out = A1@Wl^T + bias + A2@Wr^T ----------
template <int FO, bool RELU, bool OUTF32>
__global__ __launch_bounds__(256, 4) void outgemm_kernel(
    const short* __restrict__ A1, const short* __restrict__ W1,
    const short* __restrict__ A2, const short* __restrict__ W2,
    const float* __restrict__ bias,
    short* __restrict__ outB, float* __restrict__ outF, int M) {
  const int NTW = FO / 64;
  __shared__ char osm[8704];
  short* ldsO = (short*)osm;  // [32][136] bf16 path
  float* ldsF = (float*)osm;  // [32][68]  f32 path
  const int tid = threadIdx.x;
  const int wave = tid >> 6, lane = tid & 63;
  const int quad = lane >> 4, nn = lane & 15;
  const int cbase = wave * (FO / 4);
  const int row0 = blockIdx.x * 32;

  short8 w1r[4][NTW], w2r[4][NTW];
#pragma unroll
  for (int kt = 0; kt < 4; ++kt)
#pragma unroll
    for (int nt = 0; nt < NTW; ++nt) {
      w1r[kt][nt] = *(const short8*)(W1 + (size_t)(cbase + nt * 16 + nn) * HID + kt * 32 + quad * 8);
      w2r[kt][nt] = *(const short8*)(W2 + (size_t)(cbase + nt * 16 + nn) * HID + kt * 32 + quad * 8);
    }
  f32x4 bias4[NTW];
#pragma unroll
  for (int nt = 0; nt < NTW; ++nt)
#pragma unroll
    for (int r = 0; r < 4; ++r) bias4[nt][r] = bias[cbase + nt * 16 + quad * 4 + r];

  const f32x4 zero4 = {0.f, 0.f, 0.f, 0.f};
  f32x4 acc[2][NTW];
#pragma unroll
  for (int b = 0; b < 2; ++b)
#pragma unroll
    for (int nt = 0; nt < NTW; ++nt) acc[b][nt] = zero4;

#pragma unroll
  for (int kt = 0; kt < 4; ++kt) {
    int r0 = row0 + nn;      if (r0 > M - 1) r0 = M - 1;
    int r1 = row0 + 16 + nn; if (r1 > M - 1) r1 = M - 1;
    short8 a10 = *(const short8*)(A1 + (size_t)r0 * HID + kt * 32 + quad * 8);
    short8 a11 = *(const short8*)(A1 + (size_t)r1 * HID + kt * 32 + quad * 8);
    short8 a20 = *(const short8*)(A2 + (size_t)r0 * HID + kt * 32 + quad * 8);
    short8 a21 = *(const short8*)(A2 + (size_t)r1 * HID + kt * 32 + quad * 8);
#pragma unroll
    for (int nt = 0; nt < NTW; ++nt) {
      acc[0][nt] = __builtin_amdgcn_mfma_f32_16x16x32_bf16(w1r[kt][nt], a10, acc[0][nt], 0, 0, 0);
      acc[1][nt] = __builtin_amdgcn_mfma_f32_16x16x32_bf16(w1r[kt][nt], a11, acc[1][nt], 0, 0, 0);
      acc[0][nt] = __builtin_amdgcn_mfma_f32_16x16x32_bf16(w2r[kt][nt], a20, acc[0][nt], 0, 0, 0);
      acc[1][nt] = __builtin_amdgcn_mfma_f32_16x16x32_bf16(w2r[kt][nt], a21, acc[1][nt], 0, 0, 0);
    }
  }
#pragma unroll
  for (int b = 0; b < 2; ++b)
#pragma unroll
    for (int nt = 0; nt < NTW; ++nt) {
      f32x4 v = acc[b][nt] + bias4[nt];
      if (RELU) {
#pragma unroll
        for (int r = 0; r < 4; ++r) v[r] = fmaxf(v[r], 0.0f);
      }
      int lrow = b * 16 + nn;
      if (OUTF32) {
        *(f32x4*)(ldsF + lrow * 68 + cbase + nt * 16 + quad * 4) = v;
      } else {
        uint2 pk;
        pk.x = pack_bf2(v[0], v[1]);
        pk.y = pack_bf2(v[2], v[3]);
        *(uint2*)(ldsO + lrow * 136 + cbase + nt * 16 + quad * 4) = pk;
      }
    }
  BAR_LGKM();
  if (OUTF32) {
#pragma unroll
    for (int idx = tid; idx < 32 * 16; idx += 256) {
      int row = idx >> 4, c4 = (idx & 15) * 4;
      if (row0 + row < M)
        *(f32x4*)(outF + (size_t)(row0 + row) * 64 + c4) = *(const f32x4*)(ldsF + row * 68 + c4);
    }
  } else {
#pragma unroll
    for (int idx = tid; idx < 32 * 16; idx += 256) {
      int row = idx >> 4, c8 = (idx & 15) * 8;
      if (row0 + row < M)
        *(short8*)(outB + (size_t)(row0 + row) * 128 + c8) = *(const short8*)(ldsO + row * 136 + c8);
    }
  }
}

// ------- persistent LSTM recurrence: NPB=16, double-buffered P and h --------
// 512 thr = 8 waves, 16 nodes. Wave w holds Whh rows [q*128 + w*16, +16) for
// all 4 gates (64 VGPRs); acc is only 16 regs -> stays in VGPRs (no accvgpr
// moves). ldsP and ldsH are double-buffered: gather(t+1) is issued at the TOP
// of step t into the other P-buffer (previous step's barrier certifies all
// readers done), and the pre-cell fence is `s_waitcnt vmcnt(2)` -- the two
// just-issued prefetches stay in flight, gather(t) has a full step of cover.
// h double-buffer removes the WAR on h, so barrier-1 is purely the P fence.
#define NPB 16
#define PSTR 520  // 260 words: bank spread (4*nn+2*quad)%32 -> 2-way (free)
#define HSTR 136
#define LSTM_LDS_BYTES ((2 * NPB * PSTR + 2 * NPB * HSTR) * 2 + 256 * 4)  // 43008

__global__ __launch_bounds__(512, 4) void lstm_steps_kernel(
    const short* __restrict__ P, const short* __restrict__ Whh,
    const int* __restrict__ src, short* __restrict__ aggr, int M) {
  extern __shared__ char smem[];
  short* Pb = (short*)smem;                    // [2][16][520]
  short* Hb = Pb + 2 * NPB * PSTR;             // [2][16][136]
  int* srcL = (int*)(Hb + 2 * NPB * HSTR);     // [256]

  const int tid = threadIdx.x;
  const int wave = tid >> 6, lane = tid & 63;
  const int quad = lane >> 4, nn = lane & 15;
  const int nodeBase = blockIdx.x * NPB;
  const int r0row = wave * 2, r1row = wave * 2 + 1;

  // Whh fragments: for each gate q, rows [q*128 + wave*16, +16)
  short8 wreg[4][4];  // [kt][q] = 64 VGPRs
#pragma unroll
  for (int kt = 0; kt < 4; ++kt)
#pragma unroll
    for (int q = 0; q < 4; ++q)
      wreg[kt][q] = *(const short8*)(Whh + (size_t)(q * 128 + wave * 16 + nn) * HID + kt * 32 + quad * 8);

  if (tid < 256) {
    int node = nodeBase + (tid >> 4);
    srcL[tid] = (node < M) ? src[nodeBase * 16 + tid] : 0;
  }

  float c_st[4] = {0.f, 0.f, 0.f, 0.f};

  __syncthreads();  // srcL visible (full drain OK once)

  // prologue: gather(0) into P-buf0 (2 rows/wave, 1KB each, lane*16B)
  int sA = srcL[r0row * 16 + 0], sB = srcL[r1row * 16 + 0];
  __builtin_amdgcn_global_load_lds(
      (const __attribute__((address_space(1))) unsigned int*)(P + (size_t)sA * 512 + lane * 8),
      (__attribute__((address_space(3))) unsigned int*)(Pb + r0row * PSTR), 16, 0, 0);
  __builtin_amdgcn_global_load_lds(
      (const __attribute__((address_space(1))) unsigned int*)(P + (size_t)sB * 512 + lane * 8),
      (__attribute__((address_space(3))) unsigned int*)(Pb + r1row * PSTR), 16, 0, 0);
  sA = srcL[r0row * 16 + 1];
  sB = srcL[r1row * 16 + 1];

  const f32x4 zero4 = {0.f, 0.f, 0.f, 0.f};

#pragma unroll 1
  for (int t = 0; t < 16; ++t) {
    short* Pc = Pb + (t & 1) * NPB * PSTR;
    short* Pn = Pb + ((t + 1) & 1) * NPB * PSTR;
    short* Hp = Hb + ((t + 1) & 1) * NPB * HSTR;  // h(t-1) buffer
    short* Hw = Hb + (t & 1) * NPB * HSTR;        // h(t) buffer

    // ---- issue gather(t+1) into the other P-buffer (t=15: harmless dummy) ----
    __builtin_amdgcn_global_load_lds(
        (const __attribute__((address_space(1))) unsigned int*)(P + (size_t)sA * 512 + lane * 8),
        (__attribute__((address_space(3))) unsigned int*)(Pn + r0row * PSTR), 16, 0, 0);
    __builtin_amdgcn_global_load_lds(
        (const __attribute__((address_space(1))) unsigned int*)(P + (size_t)sB * 512 + lane * 8),
        (__attribute__((address_space(3))) unsigned int*)(Pn + r1row * PSTR), 16, 0, 0);

    // ---- G = Whh_rows @ h(t-1)^T : 16 MFMA, weights + acc in VGPRs ----
    f32x4 acc[4];
#pragma unroll
    for (int q = 0; q < 4; ++q) acc[q] = zero4;
    if (t) {
#pragma unroll
      for (int kt = 0; kt < 4; ++kt) {
        short8 hb = *(const short8*)(Hp + nn * HSTR + kt * 32 + quad * 8);
#pragma unroll
        for (int q = 0; q < 4; ++q)
          acc[q] = __builtin_amdgcn_mfma_f32_16x16x32_bf16(wreg[kt][q], hb, acc[q], 0, 0, 0);
      }
    }

    WAIT_VM2_BAR();  // gather(t) landed everywhere; prefetches stay in flight

    // ---- cell: lane owns (node nn, cols wave*16+quad*4..+4), gates in acc ----
    const short* pR = Pc + nn * PSTR + wave * 16 + quad * 4;
    uint2 p0 = *(const uint2*)(pR + 0 * 128);
    uint2 p1 = *(const uint2*)(pR + 1 * 128);
    uint2 p2 = *(const uint2*)(pR + 2 * 128);
    uint2 p3 = *(const uint2*)(pR + 3 * 128);
    float s0[4], s1[4], s2[4], s3[4];
    unpack2(p0.x, s0[0], s0[1]); unpack2(p0.y, s0[2], s0[3]);
    unpack2(p1.x, s1[0], s1[1]); unpack2(p1.y, s1[2], s1[3]);
    unpack2(p2.x, s2[0], s2[1]); unpack2(p2.y, s2[2], s2[3]);
    unpack2(p3.x, s3[0], s3[1]); unpack2(p3.y, s3[2], s3[3]);
    float hv[4];
#pragma unroll
    for (int r = 0; r < 4; ++r)
      hv[r] = lstm_elem(acc[0][r] + s0[r], acc[1][r] + s1[r],
                        acc[2][r] + s2[r], acc[3][r] + s3[r], c_st[r]);
    uint2 pk;
    pk.x = pack_bf2(hv[0], hv[1]);
    pk.y = pack_bf2(hv[2], hv[3]);
    *(uint2*)(Hw + nn * HSTR + wave * 16 + quad * 4) = pk;

    // ---- prefetch src indices for step t+2 (slack-covered LDS reads) ----
    int tn = (t + 2 < 16) ? t + 2 : 15;
    sA = srcL[r0row * 16 + tn];
    sB = srcL[r1row * 16 + tn];

    BAR_LGKM();  // h(t) visible; all ldsP(t) reads complete (no vmcnt drain)
  }

  // ---- final h (buf1) -> aggr ----
  if (tid < 256) {
    int rrow = tid >> 4, off = (tid & 15) * 8;
    int node = nodeBase + rrow;
    if (node < M)
      *(short8*)(aggr + (size_t)node * HID + off) = *(const short8*)(Hb + NPB * HSTR + rrow * HSTR + off);
  }
}

// ---------------- launcher ----------------
extern "C" void kernel_launch(void* const* d_in, const int* in_sizes, int n_in,
                              void* d_out, int out_size, void* d_ws, size_t ws_size,
                              hipStream_t stream) {
  const float* x = (const float*)d_in[0];
  const int* src = (const int*)d_in[1];
  const float* Wih[3] = {(const float*)d_in[2], (const float*)d_in[9], (const float*)d_in[16]};
  const float* Whh[3] = {(const float*)d_in[3], (const float*)d_in[10], (const float*)d_in[17]};
  const float* bih[3] = {(const float*)d_in[4], (const float*)d_in[11], (const float*)d_in[18]};
  const float* bhh[3] = {(const float*)d_in[5], (const float*)d_in[12], (const float*)d_in[19]};
  const float* Wl[3]  = {(const float*)d_in[6], (const float*)d_in[13], (const float*)d_in[20]};
  const float* bl[3]  = {(const float*)d_in[7], (const float*)d_in[14], (const float*)d_in[21]};
  const float* Wr[3]  = {(const float*)d_in[8], (const float*)d_in[15], (const float*)d_in[22]};

  const int M = in_sizes[0] / HID;  // 50000

  char* ws = (char*)d_ws;
  size_t off = 0;
  auto alloc = [&](size_t bytes) -> void* {
    void* p = ws + off;
    off += (bytes + 255) & ~(size_t)255;
    return p;
  };
  short* curA = (short*)alloc((size_t)M * HID * 2);
  short* curB = (short*)alloc((size_t)M * HID * 2);
  short* aggr = (short*)alloc((size_t)M * HID * 2);
  short* Pbuf = (short*)alloc((size_t)M * 512 * 2);
  short* wihB[3]; short* whhB[3]; short* wlB[3]; short* wrB[3]; float* bsum[3];
  for (int l = 0; l < 3; ++l) {
    wihB[l] = (short*)alloc(512 * HID * 2);
    whhB[l] = (short*)alloc(512 * HID * 2);
    wlB[l]  = (short*)alloc(HID * HID * 2);
    wrB[l]  = (short*)alloc(HID * HID * 2);
    bsum[l] = (float*)alloc(512 * 4);
  }

  const int nblk = (M + NPB - 1) / NPB;  // 3125
  const int ntiles = (M + 31) / 32;      // 1563

  (void)hipFuncSetAttribute((const void*)lstm_steps_kernel,
                            hipFuncAttributeMaxDynamicSharedMemorySize, LSTM_LDS_BYTES);

  // all weight conversions up-front (no inter-layer deps) + x conversion
  conv_x_kernel<<<2048, 256, 0, stream>>>(x, curA, M * HID);
  for (int l = 0; l < 3; ++l) {
    const int Fo = (l == 2) ? 64 : 128;
    conv_layer_kernel<<<256, 256, 0, stream>>>(Wih[l], Whh[l], bih[l], bhh[l], Wl[l], Wr[l],
                                               Fo * HID, wihB[l], whhB[l], wlB[l], wrB[l], bsum[l]);
  }

  short* cur = curA;
  short* nxt = curB;
  for (int l = 0; l < 3; ++l) {
    pgemm_kernel<<<512, 256, 0, stream>>>(cur, wihB[l], bsum[l], Pbuf, M, ntiles);
    lstm_steps_kernel<<<nblk, 512, LSTM_LDS_BYTES, stream>>>(Pbuf, whhB[l], src, aggr, M);
    if (l < 2) {
      outgemm_kernel<128, true, false><<<ntiles, 256, 0, stream>>>(
          aggr, wlB[l], cur, wrB[l], bl[l], nxt, nullptr, M);
      short* tswap = cur; cur = nxt; nxt = tswap;
    } else {
      outgemm_kernel<64, false, true><<<ntiles, 256, 0, stream>>>(
          aggr, wlB[l], cur, wrB[l], bl[l], nullptr, (float*)d_out, M);
    }
  }
}

// Round 8
// 797.507 us; speedup vs baseline: 8.7711x; 1.0875x over previous
//
#include <hip/hip_runtime.h>
#include <cstddef>
#include <cstdint>

typedef __attribute__((ext_vector_type(4))) float f32x4;
typedef __attribute__((ext_vector_type(8))) short short8;

#define HID 128
#define NK1 -1.4426950408889634f  // -log2(e)
#define PK2 2.8853900817779268f   // +2*log2(e)

// LDS-only barrier: no vmcnt(0) drain.
#define BAR_LGKM() __asm__ volatile("s_waitcnt lgkmcnt(0)\ns_barrier" ::: "memory")
// single per-step fence: own gathers landed + own LDS ops drained, then barrier
#define STEP_BAR() __asm__ volatile("s_waitcnt vmcnt(0) lgkmcnt(0)\ns_barrier" ::: "memory")

__device__ __forceinline__ short f2bf(float f) {
  unsigned u = __builtin_bit_cast(unsigned, f);
  u += 0x7FFFu + ((u >> 16) & 1u);
  return (short)(u >> 16);
}
// pack two f32 -> two bf16 (round-half-up) in one u32 via v_perm
__device__ __forceinline__ unsigned pack_bf2(float a, float b) {
  unsigned ua = __builtin_bit_cast(unsigned, a) + 0x8000u;
  unsigned ub = __builtin_bit_cast(unsigned, b) + 0x8000u;
  return __builtin_amdgcn_perm(ub, ua, 0x07060302u);
}
__device__ __forceinline__ void unpack2(int w, float& lo, float& hi) {
  lo = __builtin_bit_cast(float, (unsigned)(w << 16));
  hi = __builtin_bit_cast(float, (unsigned)w & 0xffff0000u);
}
__device__ __forceinline__ float2 unpack2v(int w) {
  float2 r;
  r.x = __builtin_bit_cast(float, (unsigned)(w << 16));
  r.y = __builtin_bit_cast(float, (unsigned)w & 0xffff0000u);
  return r;
}

// folded LSTM cell: inputs are PRE-SCALED pre-activations
// si,sf,so = -log2e*(gate), sg = 2log2e*(g). 5 exp2 + 2 rcp.
__device__ __forceinline__ float lstm_elem(float si, float sf, float sg, float so, float& c) {
  float Ei = __builtin_amdgcn_exp2f(si);
  float Ef = __builtin_amdgcn_exp2f(sf);
  float Tg = __builtin_amdgcn_exp2f(sg);
  float Eo = __builtin_amdgcn_exp2f(so);
  float u = 1.0f + Ei, w = 1.0f + Ef, v = Tg + 1.0f, Tm = Tg - 1.0f;
  float t0 = u * v;
  float num = __builtin_fmaf(c, t0, w * Tm);
  float cn = num * __builtin_amdgcn_rcpf(w * t0);
  c = cn;
  float Tc = __builtin_amdgcn_exp2f(PK2 * cn);
  return (Tc - 1.0f) * __builtin_amdgcn_rcpf((1.0f + Eo) * (Tc + 1.0f));
}

// ---------------- conversion kernels ----------------
__global__ void conv_x_kernel(const float* __restrict__ x, short* __restrict__ xb, int n) {
  int i = blockIdx.x * blockDim.x + threadIdx.x;
  int stride = gridDim.x * blockDim.x;
  for (; i < n; i += stride) xb[i] = f2bf(x[i]);
}

// pre-scales LSTM weights/bias by gate: i,f,o -> -log2e ; g -> +2log2e
__global__ void conv_layer_kernel(const float* __restrict__ Wih, const float* __restrict__ Whh,
                                  const float* __restrict__ bih, const float* __restrict__ bhh,
                                  const float* __restrict__ Wl, const float* __restrict__ Wr, int foK,
                                  short* __restrict__ wihB, short* __restrict__ whhB,
                                  short* __restrict__ wlB, short* __restrict__ wrB,
                                  float* __restrict__ bsum) {
  int i = blockIdx.x * blockDim.x + threadIdx.x;
  if (i < 512 * HID) {
    float sc = ((i >> 14) == 2) ? PK2 : NK1;  // gate = row>>7 = i>>14
    wihB[i] = f2bf(Wih[i] * sc);
    whhB[i] = f2bf(Whh[i] * sc);
  }
  if (i < foK) { wlB[i] = f2bf(Wl[i]); wrB[i] = f2bf(Wr[i]); }
  if (i < 512) bsum[i] = (bih[i] + bhh[i]) * (((i >> 7) == 2) ? PK2 : NK1);
}

// ------- persistent P-GEMM: P = A @ Wih^T + bias -> bf16 [M,512] -------------
// 512 thr = 8 waves; wave w owns cols [64w, +64) (wreg = 64 VGPRs) -> 4
// waves/SIMD for store-latency overlap. bias enters as MFMA C-operand.
#define OSTR 524
__global__ __launch_bounds__(512, 4) void pgemm_kernel(
    const short* __restrict__ A, const short* __restrict__ W,
    const float* __restrict__ bias, short* __restrict__ out, int M, int ntiles) {
  __shared__ short ldsO[32 * OSTR];  // 33.5 KB
  const int tid = threadIdx.x;
  const int wave = tid >> 6, lane = tid & 63;
  const int quad = lane >> 4, nn = lane & 15;
  const int cbase = wave * 64;

  short8 wreg[4][4];
#pragma unroll
  for (int kt = 0; kt < 4; ++kt)
#pragma unroll
    for (int nt = 0; nt < 4; ++nt)
      wreg[kt][nt] = *(const short8*)(W + (size_t)(cbase + nt * 16 + nn) * HID + kt * 32 + quad * 8);
  f32x4 bias4[4];
#pragma unroll
  for (int nt = 0; nt < 4; ++nt)
#pragma unroll
    for (int r = 0; r < 4; ++r) bias4[nt][r] = bias[cbase + nt * 16 + quad * 4 + r];

#pragma unroll 1
  for (int rt = blockIdx.x; rt < ntiles; rt += gridDim.x) {
    const int row0 = rt * 32;
    f32x4 acc[2][4];
#pragma unroll
    for (int b = 0; b < 2; ++b)
#pragma unroll
      for (int nt = 0; nt < 4; ++nt) acc[b][nt] = bias4[nt];
#pragma unroll
    for (int kt = 0; kt < 4; ++kt) {
      int r0 = row0 + nn;      if (r0 > M - 1) r0 = M - 1;
      int r1 = row0 + 16 + nn; if (r1 > M - 1) r1 = M - 1;
      short8 af0 = *(const short8*)(A + (size_t)r0 * HID + kt * 32 + quad * 8);
      short8 af1 = *(const short8*)(A + (size_t)r1 * HID + kt * 32 + quad * 8);
#pragma unroll
      for (int nt = 0; nt < 4; ++nt) {
        acc[0][nt] = __builtin_amdgcn_mfma_f32_16x16x32_bf16(wreg[kt][nt], af0, acc[0][nt], 0, 0, 0);
        acc[1][nt] = __builtin_amdgcn_mfma_f32_16x16x32_bf16(wreg[kt][nt], af1, acc[1][nt], 0, 0, 0);
      }
    }
    BAR_LGKM();  // previous iteration's ldsO reads complete
#pragma unroll
    for (int b = 0; b < 2; ++b)
#pragma unroll
      for (int nt = 0; nt < 4; ++nt) {
        uint2 pk;
        pk.x = pack_bf2(acc[b][nt][0], acc[b][nt][1]);
        pk.y = pack_bf2(acc[b][nt][2], acc[b][nt][3]);
        *(uint2*)(ldsO + (b * 16 + nn) * OSTR + cbase + nt * 16 + quad * 4) = pk;
      }
    BAR_LGKM();
#pragma unroll
    for (int idx = tid; idx < 32 * 64; idx += 512) {
      int row = idx >> 6, c8 = (idx & 63) * 8;
      if (row0 + row < M)
        *(short8*)(out + (size_t)(row0 + row) * 512 + c8) = *(const short8*)(ldsO + row * OSTR + c8);
    }
  }
}

// ---------------- fused output GEMM: out = A1@Wl^T + bias + A2@Wr^T ----------
template <int FO, bool RELU, bool OUTF32>
__global__ __launch_bounds__(256, 4) void outgemm_kernel(
    const short* __restrict__ A1, const short* __restrict__ W1,
    const short* __restrict__ A2, const short* __restrict__ W2,
    const float* __restrict__ bias,
    short* __restrict__ outB, float* __restrict__ outF, int M) {
  const int NTW = FO / 64;
  __shared__ char osm[8704];
  short* ldsO = (short*)osm;  // [32][136] bf16 path
  float* ldsF = (float*)osm;  // [32][68]  f32 path
  const int tid = threadIdx.x;
  const int wave = tid >> 6, lane = tid & 63;
  const int quad = lane >> 4, nn = lane & 15;
  const int cbase = wave * (FO / 4);
  const int row0 = blockIdx.x * 32;

  short8 w1r[4][NTW], w2r[4][NTW];
#pragma unroll
  for (int kt = 0; kt < 4; ++kt)
#pragma unroll
    for (int nt = 0; nt < NTW; ++nt) {
      w1r[kt][nt] = *(const short8*)(W1 + (size_t)(cbase + nt * 16 + nn) * HID + kt * 32 + quad * 8);
      w2r[kt][nt] = *(const short8*)(W2 + (size_t)(cbase + nt * 16 + nn) * HID + kt * 32 + quad * 8);
    }
  f32x4 acc[2][NTW];
#pragma unroll
  for (int b = 0; b < 2; ++b)
#pragma unroll
    for (int nt = 0; nt < NTW; ++nt)
#pragma unroll
      for (int r = 0; r < 4; ++r) acc[b][nt][r] = bias[cbase + nt * 16 + quad * 4 + r];

#pragma unroll
  for (int kt = 0; kt < 4; ++kt) {
    int r0 = row0 + nn;      if (r0 > M - 1) r0 = M - 1;
    int r1 = row0 + 16 + nn; if (r1 > M - 1) r1 = M - 1;
    short8 a10 = *(const short8*)(A1 + (size_t)r0 * HID + kt * 32 + quad * 8);
    short8 a11 = *(const short8*)(A1 + (size_t)r1 * HID + kt * 32 + quad * 8);
    short8 a20 = *(const short8*)(A2 + (size_t)r0 * HID + kt * 32 + quad * 8);
    short8 a21 = *(const short8*)(A2 + (size_t)r1 * HID + kt * 32 + quad * 8);
#pragma unroll
    for (int nt = 0; nt < NTW; ++nt) {
      acc[0][nt] = __builtin_amdgcn_mfma_f32_16x16x32_bf16(w1r[kt][nt], a10, acc[0][nt], 0, 0, 0);
      acc[1][nt] = __builtin_amdgcn_mfma_f32_16x16x32_bf16(w1r[kt][nt], a11, acc[1][nt], 0, 0, 0);
      acc[0][nt] = __builtin_amdgcn_mfma_f32_16x16x32_bf16(w2r[kt][nt], a20, acc[0][nt], 0, 0, 0);
      acc[1][nt] = __builtin_amdgcn_mfma_f32_16x16x32_bf16(w2r[kt][nt], a21, acc[1][nt], 0, 0, 0);
    }
  }
#pragma unroll
  for (int b = 0; b < 2; ++b)
#pragma unroll
    for (int nt = 0; nt < NTW; ++nt) {
      f32x4 v = acc[b][nt];
      if (RELU) {
#pragma unroll
        for (int r = 0; r < 4; ++r) v[r] = fmaxf(v[r], 0.0f);
      }
      int lrow = b * 16 + nn;
      if (OUTF32) {
        *(f32x4*)(ldsF + lrow * 68 + cbase + nt * 16 + quad * 4) = v;
      } else {
        uint2 pk;
        pk.x = pack_bf2(v[0], v[1]);
        pk.y = pack_bf2(v[2], v[3]);
        *(uint2*)(ldsO + lrow * 136 + cbase + nt * 16 + quad * 4) = pk;
      }
    }
  BAR_LGKM();
  if (OUTF32) {
#pragma unroll
    for (int idx = tid; idx < 32 * 16; idx += 256) {
      int row = idx >> 4, c4 = (idx & 15) * 4;
      if (row0 + row < M)
        *(f32x4*)(outF + (size_t)(row0 + row) * 64 + c4) = *(const f32x4*)(ldsF + row * 68 + c4);
    }
  } else {
#pragma unroll
    for (int idx = tid; idx < 32 * 16; idx += 256) {
      int row = idx >> 4, c8 = (idx & 15) * 8;
      if (row0 + row < M)
        *(short8*)(outB + (size_t)(row0 + row) * 128 + c8) = *(const short8*)(ldsO + row * 136 + c8);
    }
  }
}

// ------- persistent LSTM: single barrier/step, P as MFMA C-operand ----------
// 512 thr = 8 waves, 16 nodes/tile, grid-stride persistent over tiles (wreg
// loaded once). Per step: [wait vm0+lgkm0; barrier] -> read P-frags from Pc
// and unpack INTO acc (C-operand: no zero-init, no cell-phase adds) -> issue
// gather(t+1) into Pn -> MFMA acc += Whh@h^T -> cell -> h write. Both P and h
// double-buffered; all hazards certified by the one step-top barrier.
// HSTR=152 (word-stride 76 = 12 mod 32) de-aliases the MFMA h-reads (was
// 8-way at 136).
#define NPB 16
#define PSTR 520
#define HSTR 152
#define LSTM_LDS_BYTES ((2 * NPB * PSTR + 2 * NPB * HSTR) * 2 + 256 * 4)  // 44032

__global__ __launch_bounds__(512, 4) void lstm_steps_kernel(
    const short* __restrict__ P, const short* __restrict__ Whh,
    const int* __restrict__ src, short* __restrict__ aggr, int M, int ntiles) {
  extern __shared__ char smem[];
  short* Pb = (short*)smem;                 // [2][16][520]
  short* Hb = Pb + 2 * NPB * PSTR;          // [2][16][152]
  int* srcL = (int*)(Hb + 2 * NPB * HSTR);  // [256]

  const int tid = threadIdx.x;
  const int wave = tid >> 6, lane = tid & 63;
  const int quad = lane >> 4, nn = lane & 15;
  const int r0row = wave * 2, r1row = wave * 2 + 1;

  // Whh fragments: for each gate q, rows [q*128 + wave*16, +16)  (64 VGPRs)
  short8 wreg[4][4];  // [kt][q]
#pragma unroll
  for (int kt = 0; kt < 4; ++kt)
#pragma unroll
    for (int q = 0; q < 4; ++q)
      wreg[kt][q] = *(const short8*)(Whh + (size_t)(q * 128 + wave * 16 + nn) * HID + kt * 32 + quad * 8);

#pragma unroll 1
  for (int tile = blockIdx.x; tile < ntiles; tile += gridDim.x) {
    const int nodeBase = tile * NPB;
    if (tid < 256) {
      int node = nodeBase + (tid >> 4);
      srcL[tid] = (node < M) ? src[nodeBase * 16 + tid] : 0;
    }
    float c_st[4] = {0.f, 0.f, 0.f, 0.f};
    BAR_LGKM();  // srcL visible; prev tile's copyout reads done

    // prologue: gather(0) into P-buf0
    int sA = srcL[r0row * 16 + 0], sB = srcL[r1row * 16 + 0];
    __builtin_amdgcn_global_load_lds(
        (const __attribute__((address_space(1))) unsigned int*)(P + (size_t)sA * 512 + lane * 8),
        (__attribute__((address_space(3))) unsigned int*)(Pb + r0row * PSTR), 16, 0, 0);
    __builtin_amdgcn_global_load_lds(
        (const __attribute__((address_space(1))) unsigned int*)(P + (size_t)sB * 512 + lane * 8),
        (__attribute__((address_space(3))) unsigned int*)(Pb + r1row * PSTR), 16, 0, 0);
    sA = srcL[r0row * 16 + 1];
    sB = srcL[r1row * 16 + 1];

#pragma unroll 1
    for (int t = 0; t < 16; ++t) {
      short* Pc = Pb + (t & 1) * NPB * PSTR;
      short* Pn = Pb + ((t + 1) & 1) * NPB * PSTR;
      const short* Hp = Hb + ((t + 1) & 1) * NPB * HSTR;  // h(t-1)
      short* Hw = Hb + (t & 1) * NPB * HSTR;              // h(t)

      STEP_BAR();  // gather(t) landed everywhere; h(t-1)/LDS drained

      // ---- read P-frags and unpack INTO acc (MFMA C-operand) ----
      const short* pR = Pc + nn * PSTR + wave * 16 + quad * 4;
      uint2 p0 = *(const uint2*)(pR + 0 * 128);
      uint2 p1 = *(const uint2*)(pR + 1 * 128);
      uint2 p2 = *(const uint2*)(pR + 2 * 128);
      uint2 p3 = *(const uint2*)(pR + 3 * 128);
      f32x4 acc[4];
      {
        float2 a0 = unpack2v(p0.x), a1 = unpack2v(p0.y);
        acc[0][0] = a0.x; acc[0][1] = a0.y; acc[0][2] = a1.x; acc[0][3] = a1.y;
        float2 b0 = unpack2v(p1.x), b1 = unpack2v(p1.y);
        acc[1][0] = b0.x; acc[1][1] = b0.y; acc[1][2] = b1.x; acc[1][3] = b1.y;
        float2 c0 = unpack2v(p2.x), c1 = unpack2v(p2.y);
        acc[2][0] = c0.x; acc[2][1] = c0.y; acc[2][2] = c1.x; acc[2][3] = c1.y;
        float2 d0 = unpack2v(p3.x), d1 = unpack2v(p3.y);
        acc[3][0] = d0.x; acc[3][1] = d0.y; acc[3][2] = d1.x; acc[3][3] = d1.y;
      }

      // ---- issue gather(t+1) into the other P-buffer ----
      if (t < 15) {
        __builtin_amdgcn_global_load_lds(
            (const __attribute__((address_space(1))) unsigned int*)(P + (size_t)sA * 512 + lane * 8),
            (__attribute__((address_space(3))) unsigned int*)(Pn + r0row * PSTR), 16, 0, 0);
        __builtin_amdgcn_global_load_lds(
            (const __attribute__((address_space(1))) unsigned int*)(P + (size_t)sB * 512 + lane * 8),
            (__attribute__((address_space(3))) unsigned int*)(Pn + r1row * PSTR), 16, 0, 0);
        int tn = (t + 2 < 16) ? t + 2 : 15;
        sA = srcL[r0row * 16 + tn];
        sB = srcL[r1row * 16 + tn];
      }

      // ---- acc += Whh_rows @ h(t-1)^T ----
      if (t) {
#pragma unroll
        for (int kt = 0; kt < 4; ++kt) {
          short8 hb = *(const short8*)(Hp + nn * HSTR + kt * 32 + quad * 8);
#pragma unroll
          for (int q = 0; q < 4; ++q)
            acc[q] = __builtin_amdgcn_mfma_f32_16x16x32_bf16(wreg[kt][q], hb, acc[q], 0, 0, 0);
        }
      }

      // ---- cell: pure register math, write h(t) ----
      float hv[4];
#pragma unroll
      for (int r = 0; r < 4; ++r)
        hv[r] = lstm_elem(acc[0][r], acc[1][r], acc[2][r], acc[3][r], c_st[r]);
      uint2 pk;
      pk.x = pack_bf2(hv[0], hv[1]);
      pk.y = pack_bf2(hv[2], hv[3]);
      *(uint2*)(Hw + nn * HSTR + wave * 16 + quad * 4) = pk;
    }

    BAR_LGKM();  // h(15) visible (buf1)
    if (tid < 256) {
      int rrow = tid >> 4, off = (tid & 15) * 8;
      int node = nodeBase + rrow;
      if (node < M)
        *(short8*)(aggr + (size_t)node * HID + off) = *(const short8*)(Hb + NPB * HSTR + rrow * HSTR + off);
    }
  }
}

// ---------------- launcher ----------------
extern "C" void kernel_launch(void* const* d_in, const int* in_sizes, int n_in,
                              void* d_out, int out_size, void* d_ws, size_t ws_size,
                              hipStream_t stream) {
  const float* x = (const float*)d_in[0];
  const int* src = (const int*)d_in[1];
  const float* Wih[3] = {(const float*)d_in[2], (const float*)d_in[9], (const float*)d_in[16]};
  const float* Whh[3] = {(const float*)d_in[3], (const float*)d_in[10], (const float*)d_in[17]};
  const float* bih[3] = {(const float*)d_in[4], (const float*)d_in[11], (const float*)d_in[18]};
  const float* bhh[3] = {(const float*)d_in[5], (const float*)d_in[12], (const float*)d_in[19]};
  const float* Wl[3]  = {(const float*)d_in[6], (const float*)d_in[13], (const float*)d_in[20]};
  const float* bl[3]  = {(const float*)d_in[7], (const float*)d_in[14], (const float*)d_in[21]};
  const float* Wr[3]  = {(const float*)d_in[8], (const float*)d_in[15], (const float*)d_in[22]};

  const int M = in_sizes[0] / HID;  // 50000

  char* ws = (char*)d_ws;
  size_t off = 0;
  auto alloc = [&](size_t bytes) -> void* {
    void* p = ws + off;
    off += (bytes + 255) & ~(size_t)255;
    return p;
  };
  short* curA = (short*)alloc((size_t)M * HID * 2);
  short* curB = (short*)alloc((size_t)M * HID * 2);
  short* aggr = (short*)alloc((size_t)M * HID * 2);
  short* Pbuf = (short*)alloc((size_t)M * 512 * 2);
  short* wihB[3]; short* whhB[3]; short* wlB[3]; short* wrB[3]; float* bsum[3];
  for (int l = 0; l < 3; ++l) {
    wihB[l] = (short*)alloc(512 * HID * 2);
    whhB[l] = (short*)alloc(512 * HID * 2);
    wlB[l]  = (short*)alloc(HID * HID * 2);
    wrB[l]  = (short*)alloc(HID * HID * 2);
    bsum[l] = (float*)alloc(512 * 4);
  }

  const int nltiles = (M + NPB - 1) / NPB;  // 3125
  const int ntiles = (M + 31) / 32;         // 1563

  (void)hipFuncSetAttribute((const void*)lstm_steps_kernel,
                            hipFuncAttributeMaxDynamicSharedMemorySize, LSTM_LDS_BYTES);

  conv_x_kernel<<<2048, 256, 0, stream>>>(x, curA, M * HID);
  for (int l = 0; l < 3; ++l) {
    const int Fo = (l == 2) ? 64 : 128;
    conv_layer_kernel<<<256, 256, 0, stream>>>(Wih[l], Whh[l], bih[l], bhh[l], Wl[l], Wr[l],
                                               Fo * HID, wihB[l], whhB[l], wlB[l], wrB[l], bsum[l]);
  }

  short* cur = curA;
  short* nxt = curB;
  for (int l = 0; l < 3; ++l) {
    pgemm_kernel<<<1024, 512, 0, stream>>>(cur, wihB[l], bsum[l], Pbuf, M, ntiles);
    lstm_steps_kernel<<<512, 512, LSTM_LDS_BYTES, stream>>>(Pbuf, whhB[l], src, aggr, M, nltiles);
    if (l < 2) {
      outgemm_kernel<128, true, false><<<ntiles, 256, 0, stream>>>(
          aggr, wlB[l], cur, wrB[l], bl[l], nxt, nullptr, M);
      short* tswap = cur; cur = nxt; nxt = tswap;
    } else {
      outgemm_kernel<64, false, true><<<ntiles, 256, 0, stream>>>(
          aggr, wlB[l], cur, wrB[l], bl[l], nullptr, (float*)d_out, M);
    }
  }
}